// Round 1
// baseline (306.810 us; speedup 1.0000x reference)
//
#include <hip/hip_runtime.h>
#include <math.h>

// Problem constants
static constexpr int NB   = 16;    // batch
static constexpr int DIM  = 256;   // total channels
static constexpr int CG   = 64;    // global-branch channels
static constexpr int HH   = 64;
static constexpr int WW   = 64;
static constexpr int HW   = HH * WW;   // 4096

__device__ __forceinline__ float softplus_f(float x) {
    return fmaxf(x, 0.f) + log1pf(expf(-fabsf(x)));
}
__device__ __forceinline__ float silu_f(float x) {
    return x / (1.f + expf(-x));
}
__device__ __forceinline__ float mish_f(float x) {
    return x * tanhf(softplus_f(x));
}

// ---------------------------------------------------------------------------
// Passthrough: out[:,128:256] = x[:,128:256]   (identical flat indices)
// ---------------------------------------------------------------------------
__global__ __launch_bounds__(256) void k_copy_xi(const float4* __restrict__ x,
                                                 float4* __restrict__ out) {
    int i = blockIdx.x * 256 + threadIdx.x;            // 16*128*1024 float4
    const int per_b = 128 * HW / 4;                    // 131072
    int b = i / per_b, r = i % per_b;
    int idx = b * (DIM * HW / 4) + per_b + r;
    out[idx] = x[idx];
}

// ---------------------------------------------------------------------------
// Local branch: per-(b,c) channel mean of xl
// ---------------------------------------------------------------------------
__global__ __launch_bounds__(256) void k_mean(const float* __restrict__ x,
                                              float* __restrict__ mean) {
    int bc = blockIdx.x;                 // b*64 + c
    int b = bc >> 6, c = bc & 63;
    const float* p = x + ((size_t)b * DIM + 64 + c) * HW;
    float s = 0.f;
    for (int i = threadIdx.x; i < HW; i += 256) s += p[i];
    __shared__ float red[256];
    red[threadIdx.x] = s;
    __syncthreads();
    for (int o = 128; o > 0; o >>= 1) {
        if (threadIdx.x < o) red[threadIdx.x] += red[threadIdx.x + o];
        __syncthreads();
    }
    if (threadIdx.x == 0) mean[bc] = red[0] * (1.f / HW);
}

// ---------------------------------------------------------------------------
// gates = softmax(mean @ gw.T); weff[b,c,:] = (sum_e g_e * ew[e,c]) * bn1scale
// ---------------------------------------------------------------------------
__global__ void k_weff(const float* __restrict__ mean,
                       const float* __restrict__ ew,
                       const float* __restrict__ gw,
                       const float* __restrict__ bn1g,
                       float* __restrict__ weff, int k2) {
    int b = blockIdx.x;
    int c = threadIdx.x;                 // 64 threads
    __shared__ float m[64];
    __shared__ float g[4];
    m[c] = mean[b * 64 + c];
    __syncthreads();
    if (c < 4) {
        float l = 0.f;
        for (int cc = 0; cc < 64; ++cc) l += m[cc] * gw[c * 64 + cc];
        g[c] = l;
    }
    __syncthreads();
    if (c == 0) {
        float mx = fmaxf(fmaxf(g[0], g[1]), fmaxf(g[2], g[3]));
        float e0 = expf(g[0] - mx), e1 = expf(g[1] - mx);
        float e2 = expf(g[2] - mx), e3 = expf(g[3] - mx);
        float inv = 1.f / (e0 + e1 + e2 + e3);
        g[0] = e0 * inv; g[1] = e1 * inv; g[2] = e2 * inv; g[3] = e3 * inv;
    }
    __syncthreads();
    float g1s = bn1g[c] * rsqrtf(1.f + 1e-5f);
    for (int kk = 0; kk < k2; ++kk) {
        float w = 0.f;
        for (int e = 0; e < 4; ++e) w += g[e] * ew[(e * 64 + c) * k2 + kk];
        weff[(b * 64 + c) * k2 + kk] = w * g1s;
    }
}

// ---------------------------------------------------------------------------
// Local branch conv: 3 depthwise convs (3/5/7) + mish/affine chain, summed.
// One block per (b, c, 32x32 tile). LDS tile with halo 3.
// ---------------------------------------------------------------------------
__global__ __launch_bounds__(256) void k_local(
    const float* __restrict__ x,
    const float* __restrict__ w3, const float* __restrict__ w5, const float* __restrict__ w7,
    const float* __restrict__ b1_0, const float* __restrict__ pw0,
    const float* __restrict__ g2_0, const float* __restrict__ b2_0,
    const float* __restrict__ b1_1, const float* __restrict__ pw1,
    const float* __restrict__ g2_1, const float* __restrict__ b2_1,
    const float* __restrict__ b1_2, const float* __restrict__ pw2,
    const float* __restrict__ g2_2, const float* __restrict__ b2_2,
    float* __restrict__ out) {
    int tile = blockIdx.x;               // 0..3
    int c = blockIdx.y, b = blockIdx.z;
    int oy = (tile >> 1) * 32, ox = (tile & 1) * 32;
    __shared__ float t[38 * 38];
    __shared__ float kw[83];
    const float* xp = x + ((size_t)b * DIM + 64 + c) * HW;
    for (int i = threadIdx.x; i < 38 * 38; i += 256) {
        int yy = i / 38 - 3 + oy, xx = i % 38 - 3 + ox;
        t[i] = (yy >= 0 && yy < 64 && xx >= 0 && xx < 64) ? xp[yy * 64 + xx] : 0.f;
    }
    if (threadIdx.x < 9)       kw[threadIdx.x] = w3[(b * 64 + c) * 9 + threadIdx.x];
    else if (threadIdx.x < 34) kw[threadIdx.x] = w5[(b * 64 + c) * 25 + threadIdx.x - 9];
    else if (threadIdx.x < 83) kw[threadIdx.x] = w7[(b * 64 + c) * 49 + threadIdx.x - 34];
    __syncthreads();
    const float rs = rsqrtf(1.f + 1e-5f);
    float bb1a = b1_0[c], bb1b = b1_1[c], bb1c = b1_2[c];
    float ssa = pw0[c] * g2_0[c] * rs, ssb = pw1[c] * g2_1[c] * rs, ssc = pw2[c] * g2_2[c] * rs;
    float bb2a = b2_0[c], bb2b = b2_1[c], bb2c = b2_2[c];
    float* op = out + ((size_t)b * DIM + 64 + c) * HW;
    for (int i = threadIdx.x; i < 1024; i += 256) {
        int y = i >> 5, xq = i & 31;
        float s3 = 0.f, s5 = 0.f, s7 = 0.f;
#pragma unroll
        for (int dy = 0; dy < 7; ++dy)
#pragma unroll
            for (int dx = 0; dx < 7; ++dx)
                s7 = fmaf(t[(y + dy) * 38 + xq + dx], kw[34 + dy * 7 + dx], s7);
#pragma unroll
        for (int dy = 0; dy < 5; ++dy)
#pragma unroll
            for (int dx = 0; dx < 5; ++dx)
                s5 = fmaf(t[(y + 1 + dy) * 38 + xq + 1 + dx], kw[9 + dy * 5 + dx], s5);
#pragma unroll
        for (int dy = 0; dy < 3; ++dy)
#pragma unroll
            for (int dx = 0; dx < 3; ++dx)
                s3 = fmaf(t[(y + 2 + dy) * 38 + xq + 2 + dx], kw[dy * 3 + dx], s3);
        float r = mish_f(s3 + bb1a) * ssa + bb2a
                + mish_f(s5 + bb1b) * ssb + bb2b
                + mish_f(s7 + bb1c) * ssc + bb2c;
        op[(oy + y) * 64 + ox + xq] = r;
    }
}

// ---------------------------------------------------------------------------
// Fused wavelet: Haar decompose -> depthwise 3x3 conv + bias, *scale -> Haar rec.
// One block per (b, c): full 64x64 plane in LDS.
// ---------------------------------------------------------------------------
__global__ __launch_bounds__(256) void k_up(const float* __restrict__ x,
                                            const float* __restrict__ wav_w,
                                            const float* __restrict__ wav_b,
                                            const float* __restrict__ wav_scale,
                                            float* __restrict__ up) {
    int c = blockIdx.x, b = blockIdx.y;
    __shared__ float xs[64 * 65];
    __shared__ float wt[4][32 * 33];
    const float* xp = x + ((size_t)b * DIM + c) * HW;
    for (int i = threadIdx.x; i < HW; i += 256) xs[(i >> 6) * 65 + (i & 63)] = xp[i];
    __syncthreads();
    for (int i = threadIdx.x; i < 1024; i += 256) {
        int h = i >> 5, w = i & 31;
        float a  = xs[(2 * h) * 65 + 2 * w],     bb = xs[(2 * h) * 65 + 2 * w + 1];
        float cc = xs[(2 * h + 1) * 65 + 2 * w], dd = xs[(2 * h + 1) * 65 + 2 * w + 1];
        wt[0][h * 33 + w] = 0.5f * (a + bb + cc + dd);
        wt[1][h * 33 + w] = 0.5f * (a + bb - cc - dd);
        wt[2][h * 33 + w] = 0.5f * (a - bb + cc - dd);
        wt[3][h * 33 + w] = 0.5f * (a - bb - cc + dd);
    }
    __syncthreads();
    float wk[4][9], tb[4];
#pragma unroll
    for (int k = 0; k < 4; ++k) {
        int ch = c * 4 + k;
        float sc = wav_scale[ch];
#pragma unroll
        for (int j = 0; j < 9; ++j) wk[k][j] = wav_w[ch * 9 + j] * sc;
        tb[k] = wav_b[ch] * sc;
    }
    float* upp = up + ((size_t)b * CG + c) * HW;
    for (int i = threadIdx.x; i < 1024; i += 256) {
        int h = i >> 5, w = i & 31;
        float tg[4];
#pragma unroll
        for (int k = 0; k < 4; ++k) {
            float s = tb[k];
#pragma unroll
            for (int dy = -1; dy <= 1; ++dy) {
                int hh = h + dy;
                if (hh < 0 || hh >= 32) continue;
#pragma unroll
                for (int dx = -1; dx <= 1; ++dx) {
                    int wx = w + dx;
                    if (wx < 0 || wx >= 32) continue;
                    s = fmaf(wt[k][hh * 33 + wx], wk[k][(dy + 1) * 3 + (dx + 1)], s);
                }
            }
            tg[k] = s;
        }
        float u00 = 0.5f * (tg[0] - tg[1] - tg[2] + tg[3]);
        float u01 = 0.5f * (tg[0] - tg[1] + tg[2] - tg[3]);
        float u10 = 0.5f * (tg[0] + tg[1] - tg[2] - tg[3]);
        float u11 = 0.5f * (tg[0] + tg[1] + tg[2] + tg[3]);
        upp[(2 * h) * 64 + 2 * w]         = u00;
        upp[(2 * h) * 64 + 2 * w + 1]     = u01;
        upp[(2 * h + 1) * 64 + 2 * w]     = u10;
        upp[(2 * h + 1) * 64 + 2 * w + 1] = u11;
    }
}

// ---------------------------------------------------------------------------
// SS2D input projection: xz = in_w(128x64) @ xg per pixel. Block per (b, h row).
// ---------------------------------------------------------------------------
__global__ __launch_bounds__(256) void k_inproj(const float* __restrict__ x,
                                                const float* __restrict__ in_w,
                                                float* __restrict__ xi,
                                                float* __restrict__ z) {
    int h = blockIdx.x, b = blockIdx.y;
    __shared__ float xs[64 * 65];        // [c][w]
    __shared__ float wl[128 * 64];
    for (int i = threadIdx.x; i < 64 * 64; i += 256) {
        int c = i >> 6, w = i & 63;
        xs[c * 65 + w] = x[((size_t)b * DIM + c) * HW + h * 64 + w];
    }
    for (int i = threadIdx.x; i < 128 * 64; i += 256) wl[i] = in_w[i];
    __syncthreads();
    int lane = threadIdx.x & 63;
    int wave = threadIdx.x >> 6;
    float acc[32];
#pragma unroll
    for (int oi = 0; oi < 32; ++oi) acc[oi] = 0.f;
    for (int c = 0; c < 64; ++c) {
        float xv = xs[c * 65 + lane];
#pragma unroll
        for (int oi = 0; oi < 32; ++oi)
            acc[oi] = fmaf(wl[(wave * 32 + oi) * 64 + c], xv, acc[oi]);
    }
#pragma unroll
    for (int oi = 0; oi < 32; ++oi) {
        int o = wave * 32 + oi;
        float* dst = (o < 64) ? (xi + ((size_t)b * 64 + o) * HW + h * 64)
                              : (z + ((size_t)b * 64 + (o - 64)) * HW + h * 64);
        dst[lane] = acc[oi];
    }
}

// ---------------------------------------------------------------------------
// xc = silu(depthwise3x3(xi) + cb). Block per (b, c) plane.
// ---------------------------------------------------------------------------
__global__ __launch_bounds__(256) void k_dwss(const float* __restrict__ xi,
                                              const float* __restrict__ cw,
                                              const float* __restrict__ cb,
                                              float* __restrict__ xc) {
    int c = blockIdx.x, b = blockIdx.y;
    __shared__ float t[66 * 66];
    const float* p = xi + ((size_t)b * 64 + c) * HW;
    for (int i = threadIdx.x; i < 66 * 66; i += 256) {
        int y = i / 66 - 1, xq = i % 66 - 1;
        t[i] = (y >= 0 && y < 64 && xq >= 0 && xq < 64) ? p[y * 64 + xq] : 0.f;
    }
    __syncthreads();
    float wk[9];
#pragma unroll
    for (int j = 0; j < 9; ++j) wk[j] = cw[c * 9 + j];
    float bias = cb[c];
    float* q = xc + ((size_t)b * 64 + c) * HW;
    for (int i = threadIdx.x; i < HW; i += 256) {
        int y = i >> 6, xq = i & 63;
        float s = bias;
#pragma unroll
        for (int dy = 0; dy < 3; ++dy)
#pragma unroll
            for (int dx = 0; dx < 3; ++dx)
                s = fmaf(t[(y + dy) * 66 + xq + dx], wk[dy * 3 + dx], s);
        q[i] = silu_f(s);
    }
}

// ---------------------------------------------------------------------------
// Per-pixel 6-way projections for both scan directions (dt[4], B, C).
// proj layout: [dir][b][l][8]
// ---------------------------------------------------------------------------
__global__ __launch_bounds__(256) void k_ssproj(const float* __restrict__ xc,
                                                const float* __restrict__ xpw,
                                                float* __restrict__ proj) {
    int h = blockIdx.x, b = blockIdx.y;
    __shared__ float xs[64 * 65];
    for (int i = threadIdx.x; i < 64 * 64; i += 256) {
        int c = i >> 6, w = i & 63;
        xs[c * 65 + w] = xc[((size_t)b * 64 + c) * HW + h * 64 + w];
    }
    __syncthreads();
    int w = threadIdx.x & 63;
    int j = threadIdx.x >> 6;
    for (int m = 0; m < 3; ++m) {
        int pidx = j * 3 + m;
        int dir = pidx / 6, e = pidx % 6;
        float s = 0.f;
        for (int c = 0; c < 64; ++c)
            s = fmaf(xs[c * 65 + w], xpw[(dir * 6 + e) * 64 + c], s);
        int l = (dir == 0) ? (h * 64 + w) : (w * 64 + h);
        proj[(((size_t)dir * NB + b) * HW + l) * 8 + e] = s;
    }
}

// ---------------------------------------------------------------------------
// Selective scan (N=1): one wave per (b, dir, d). Hillis-Steele affine scan
// within each 64-chunk, scalar carry across chunks.
// ---------------------------------------------------------------------------
__global__ __launch_bounds__(256) void k_scan(const float* __restrict__ xc,
                                              const float* __restrict__ proj,
                                              const float* __restrict__ dt_w,
                                              const float* __restrict__ dt_b,
                                              const float* __restrict__ A_log,
                                              const float* __restrict__ Dp,
                                              float* __restrict__ y0,
                                              float* __restrict__ y1) {
    int wid = blockIdx.x * 4 + (threadIdx.x >> 6);
    int lane = threadIdx.x & 63;
    int b = wid >> 7;
    int rem = wid & 127;
    int dir = rem >> 6;
    int d = rem & 63;
    int pd = dir * 64 + d;
    float w0 = dt_w[pd * 4 + 0], w1 = dt_w[pd * 4 + 1];
    float w2 = dt_w[pd * 4 + 2], w3v = dt_w[pd * 4 + 3];
    float db = dt_b[pd];
    float A = -expf(A_log[pd]);
    float Dv = Dp[pd];
    const float* pr = proj + ((size_t)dir * NB + b) * HW * 8;
    const float* uplane = xc + ((size_t)b * 64 + d) * HW;
    float* yp = ((dir == 0) ? y0 : y1) + ((size_t)b * 64 + d) * HW;
    float carry = 0.f;
    for (int i = 0; i < 64; ++i) {
        int l = i * 64 + lane;
        const float* pp = pr + (size_t)l * 8;
        float pre = fmaf(pp[0], w0, fmaf(pp[1], w1, fmaf(pp[2], w2, fmaf(pp[3], w3v, db))));
        float Bm = pp[4], Cm = pp[5];
        float u = (dir == 0) ? uplane[l] : uplane[lane * 64 + i];
        float delta = fmaxf(pre, 0.f) + log1pf(expf(-fabsf(pre)));
        float a = expf(delta * A);
        float bv = delta * Bm * u;
        float As = a, Bs = bv;
#pragma unroll
        for (int off = 1; off < 64; off <<= 1) {
            float ap = __shfl_up(As, (unsigned)off, 64);
            float bp = __shfl_up(Bs, (unsigned)off, 64);
            if (lane >= off) { Bs = fmaf(As, bp, Bs); As *= ap; }
        }
        float hcur = fmaf(As, carry, Bs);
        float yv = fmaf(hcur, Cm, Dv * u);
        if (dir == 0) yp[l] = yv;
        else          yp[lane * 64 + i] = yv;
        carry = __shfl(hcur, 63, 64);
    }
}

// ---------------------------------------------------------------------------
// Final: y=(y0+y1)*silu(z); g = ow @ y (1x1 conv); out_g = base_scale*g + up
// ---------------------------------------------------------------------------
__global__ __launch_bounds__(256) void k_final(const float* __restrict__ y0,
                                               const float* __restrict__ y1,
                                               const float* __restrict__ z,
                                               const float* __restrict__ ow,
                                               const float* __restrict__ base_scale,
                                               const float* __restrict__ up,
                                               float* __restrict__ out) {
    int h = blockIdx.x, b = blockIdx.y;
    __shared__ float yv[64 * 65];
    __shared__ float wl[64 * 64];
    for (int i = threadIdx.x; i < 64 * 64; i += 256) {
        int c = i >> 6, w = i & 63;
        size_t idx = ((size_t)b * 64 + c) * HW + h * 64 + w;
        float zz = z[idx];
        yv[c * 65 + w] = (y0[idx] + y1[idx]) * (zz / (1.f + expf(-zz)));
        wl[i] = ow[i];
    }
    __syncthreads();
    for (int i = threadIdx.x; i < 64 * 64; i += 256) {
        int o = i >> 6, w = i & 63;
        float s = 0.f;
        for (int c = 0; c < 64; ++c)
            s = fmaf(wl[o * 64 + c], yv[c * 65 + w], s);
        out[((size_t)b * DIM + o) * HW + h * 64 + w] =
            fmaf(base_scale[o], s, up[((size_t)b * CG + o) * HW + h * 64 + w]);
    }
}

// ---------------------------------------------------------------------------
extern "C" void kernel_launch(void* const* d_in, const int* in_sizes, int n_in,
                              void* d_out, int out_size, void* d_ws, size_t ws_size,
                              hipStream_t stream) {
    (void)in_sizes; (void)n_in; (void)out_size; (void)ws_size;
    const float* x = (const float*)d_in[0];
    float* out = (float*)d_out;
    float* ws = (float*)d_ws;

    const size_t IMG = (size_t)NB * 64 * HW;   // 4,194,304 floats
    float* buf_xi   = ws;                      // reused as y0 after consumption
    float* buf_z    = ws + IMG;
    float* buf_xc   = ws + 2 * IMG;
    float* buf_up   = ws + 3 * IMG;
    float* buf_y1   = ws + 4 * IMG;
    float* buf_proj = ws + 5 * IMG;            // 2*16*4096*8 = 1,048,576 floats
    float* buf_mean = buf_proj + (size_t)2 * NB * HW * 8;  // 1024
    float* buf_w3   = buf_mean + 1024;         // 16*64*9
    float* buf_w5   = buf_w3 + 16 * 64 * 9;    // 16*64*25
    float* buf_w7   = buf_w5 + 16 * 64 * 25;   // 16*64*49

    // ---- local branch ----
    k_mean<<<1024, 256, 0, stream>>>(x, buf_mean);
    k_weff<<<16, 64, 0, stream>>>(buf_mean, (const float*)d_in[1],
                                  (const float*)d_in[2], (const float*)d_in[3], buf_w3, 9);
    k_weff<<<16, 64, 0, stream>>>(buf_mean, (const float*)d_in[8],
                                  (const float*)d_in[9], (const float*)d_in[10], buf_w5, 25);
    k_weff<<<16, 64, 0, stream>>>(buf_mean, (const float*)d_in[15],
                                  (const float*)d_in[16], (const float*)d_in[17], buf_w7, 49);
    k_local<<<dim3(4, 64, 16), 256, 0, stream>>>(x, buf_w3, buf_w5, buf_w7,
        (const float*)d_in[4],  (const float*)d_in[5],  (const float*)d_in[6],  (const float*)d_in[7],
        (const float*)d_in[11], (const float*)d_in[12], (const float*)d_in[13], (const float*)d_in[14],
        (const float*)d_in[18], (const float*)d_in[19], (const float*)d_in[20], (const float*)d_in[21],
        out);

    // ---- wavelet branch (fused dec->conv->rec) ----
    k_up<<<dim3(64, 16), 256, 0, stream>>>(x, (const float*)d_in[22],
        (const float*)d_in[23], (const float*)d_in[24], buf_up);

    // ---- ss2d ----
    k_inproj<<<dim3(64, 16), 256, 0, stream>>>(x, (const float*)d_in[26], buf_xi, buf_z);
    k_dwss<<<dim3(64, 16), 256, 0, stream>>>(buf_xi, (const float*)d_in[27],
        (const float*)d_in[28], buf_xc);
    k_ssproj<<<dim3(64, 16), 256, 0, stream>>>(buf_xc, (const float*)d_in[29], buf_proj);
    k_scan<<<512, 256, 0, stream>>>(buf_xc, buf_proj,
        (const float*)d_in[30], (const float*)d_in[31],
        (const float*)d_in[32], (const float*)d_in[33],
        buf_xi /* y0 (xi is dead now) */, buf_y1);
    k_final<<<dim3(64, 16), 256, 0, stream>>>(buf_xi, buf_y1, buf_z,
        (const float*)d_in[34], (const float*)d_in[25], buf_up, out);

    // ---- passthrough ----
    k_copy_xi<<<(16 * 128 * HW / 4) / 256, 256, 0, stream>>>((const float4*)x, (float4*)out);
}

// Round 2
// 277.419 us; speedup vs baseline: 1.1059x; 1.1059x over previous
//
#include <hip/hip_runtime.h>
#include <math.h>

// Problem constants
static constexpr int NB   = 16;    // batch
static constexpr int DIM  = 256;   // total channels
static constexpr int CG   = 64;    // global-branch channels
static constexpr int HH   = 64;
static constexpr int WW   = 64;
static constexpr int HW   = HH * WW;   // 4096

__device__ __forceinline__ float softplus_f(float x) {
    return fmaxf(x, 0.f) + log1pf(expf(-fabsf(x)));
}
__device__ __forceinline__ float silu_f(float x) {
    return x / (1.f + expf(-x));
}
__device__ __forceinline__ float mish_f(float x) {
    return x * tanhf(softplus_f(x));
}

// ---------------------------------------------------------------------------
// Passthrough: out[:,128:256] = x[:,128:256]   (identical flat indices)
// ---------------------------------------------------------------------------
__global__ __launch_bounds__(256) void k_copy_xi(const float4* __restrict__ x,
                                                 float4* __restrict__ out) {
    int i = blockIdx.x * 256 + threadIdx.x;            // 16*128*1024 float4
    const int per_b = 128 * HW / 4;                    // 131072
    int b = i / per_b, r = i % per_b;
    int idx = b * (DIM * HW / 4) + per_b + r;
    out[idx] = x[idx];
}

// ---------------------------------------------------------------------------
// Local branch: per-(b,c) channel mean of xl
// ---------------------------------------------------------------------------
__global__ __launch_bounds__(256) void k_mean(const float* __restrict__ x,
                                              float* __restrict__ mean) {
    int bc = blockIdx.x;                 // b*64 + c
    int b = bc >> 6, c = bc & 63;
    const float* p = x + ((size_t)b * DIM + 64 + c) * HW;
    float s = 0.f;
    for (int i = threadIdx.x; i < HW; i += 256) s += p[i];
    __shared__ float red[256];
    red[threadIdx.x] = s;
    __syncthreads();
    for (int o = 128; o > 0; o >>= 1) {
        if (threadIdx.x < o) red[threadIdx.x] += red[threadIdx.x + o];
        __syncthreads();
    }
    if (threadIdx.x == 0) mean[bc] = red[0] * (1.f / HW);
}

// ---------------------------------------------------------------------------
// gates = softmax(mean @ gw.T); weff[b,c,:] = (sum_e g_e * ew[e,c]) * bn1scale
// ---------------------------------------------------------------------------
__global__ void k_weff(const float* __restrict__ mean,
                       const float* __restrict__ ew,
                       const float* __restrict__ gw,
                       const float* __restrict__ bn1g,
                       float* __restrict__ weff, int k2) {
    int b = blockIdx.x;
    int c = threadIdx.x;                 // 64 threads
    __shared__ float m[64];
    __shared__ float g[4];
    m[c] = mean[b * 64 + c];
    __syncthreads();
    if (c < 4) {
        float l = 0.f;
        for (int cc = 0; cc < 64; ++cc) l += m[cc] * gw[c * 64 + cc];
        g[c] = l;
    }
    __syncthreads();
    if (c == 0) {
        float mx = fmaxf(fmaxf(g[0], g[1]), fmaxf(g[2], g[3]));
        float e0 = expf(g[0] - mx), e1 = expf(g[1] - mx);
        float e2 = expf(g[2] - mx), e3 = expf(g[3] - mx);
        float inv = 1.f / (e0 + e1 + e2 + e3);
        g[0] = e0 * inv; g[1] = e1 * inv; g[2] = e2 * inv; g[3] = e3 * inv;
    }
    __syncthreads();
    float g1s = bn1g[c] * rsqrtf(1.f + 1e-5f);
    for (int kk = 0; kk < k2; ++kk) {
        float w = 0.f;
        for (int e = 0; e < 4; ++e) w += g[e] * ew[(e * 64 + c) * k2 + kk];
        weff[(b * 64 + c) * k2 + kk] = w * g1s;
    }
}

// ---------------------------------------------------------------------------
// Local branch conv: 3 depthwise convs (3/5/7) + mish/affine chain, summed.
// One block per (b, c, 32x32 tile). LDS tile with halo 3.
// ---------------------------------------------------------------------------
__global__ __launch_bounds__(256) void k_local(
    const float* __restrict__ x,
    const float* __restrict__ w3, const float* __restrict__ w5, const float* __restrict__ w7,
    const float* __restrict__ b1_0, const float* __restrict__ pw0,
    const float* __restrict__ g2_0, const float* __restrict__ b2_0,
    const float* __restrict__ b1_1, const float* __restrict__ pw1,
    const float* __restrict__ g2_1, const float* __restrict__ b2_1,
    const float* __restrict__ b1_2, const float* __restrict__ pw2,
    const float* __restrict__ g2_2, const float* __restrict__ b2_2,
    float* __restrict__ out) {
    int tile = blockIdx.x;               // 0..3
    int c = blockIdx.y, b = blockIdx.z;
    int oy = (tile >> 1) * 32, ox = (tile & 1) * 32;
    __shared__ float t[38 * 38];
    __shared__ float kw[83];
    const float* xp = x + ((size_t)b * DIM + 64 + c) * HW;
    for (int i = threadIdx.x; i < 38 * 38; i += 256) {
        int yy = i / 38 - 3 + oy, xx = i % 38 - 3 + ox;
        t[i] = (yy >= 0 && yy < 64 && xx >= 0 && xx < 64) ? xp[yy * 64 + xx] : 0.f;
    }
    if (threadIdx.x < 9)       kw[threadIdx.x] = w3[(b * 64 + c) * 9 + threadIdx.x];
    else if (threadIdx.x < 34) kw[threadIdx.x] = w5[(b * 64 + c) * 25 + threadIdx.x - 9];
    else if (threadIdx.x < 83) kw[threadIdx.x] = w7[(b * 64 + c) * 49 + threadIdx.x - 34];
    __syncthreads();
    const float rs = rsqrtf(1.f + 1e-5f);
    float bb1a = b1_0[c], bb1b = b1_1[c], bb1c = b1_2[c];
    float ssa = pw0[c] * g2_0[c] * rs, ssb = pw1[c] * g2_1[c] * rs, ssc = pw2[c] * g2_2[c] * rs;
    float bb2a = b2_0[c], bb2b = b2_1[c], bb2c = b2_2[c];
    float* op = out + ((size_t)b * DIM + 64 + c) * HW;
    for (int i = threadIdx.x; i < 1024; i += 256) {
        int y = i >> 5, xq = i & 31;
        float s3 = 0.f, s5 = 0.f, s7 = 0.f;
#pragma unroll
        for (int dy = 0; dy < 7; ++dy)
#pragma unroll
            for (int dx = 0; dx < 7; ++dx)
                s7 = fmaf(t[(y + dy) * 38 + xq + dx], kw[34 + dy * 7 + dx], s7);
#pragma unroll
        for (int dy = 0; dy < 5; ++dy)
#pragma unroll
            for (int dx = 0; dx < 5; ++dx)
                s5 = fmaf(t[(y + 1 + dy) * 38 + xq + 1 + dx], kw[9 + dy * 5 + dx], s5);
#pragma unroll
        for (int dy = 0; dy < 3; ++dy)
#pragma unroll
            for (int dx = 0; dx < 3; ++dx)
                s3 = fmaf(t[(y + 2 + dy) * 38 + xq + 2 + dx], kw[dy * 3 + dx], s3);
        float r = mish_f(s3 + bb1a) * ssa + bb2a
                + mish_f(s5 + bb1b) * ssb + bb2b
                + mish_f(s7 + bb1c) * ssc + bb2c;
        op[(oy + y) * 64 + ox + xq] = r;
    }
}

// ---------------------------------------------------------------------------
// Fused wavelet: Haar decompose -> depthwise 3x3 conv + bias, *scale -> Haar rec.
// One block per (b, c): full 64x64 plane in LDS.
// ---------------------------------------------------------------------------
__global__ __launch_bounds__(256) void k_up(const float* __restrict__ x,
                                            const float* __restrict__ wav_w,
                                            const float* __restrict__ wav_b,
                                            const float* __restrict__ wav_scale,
                                            float* __restrict__ up) {
    int c = blockIdx.x, b = blockIdx.y;
    __shared__ float xs[64 * 65];
    __shared__ float wt[4][32 * 33];
    const float* xp = x + ((size_t)b * DIM + c) * HW;
    for (int i = threadIdx.x; i < HW; i += 256) xs[(i >> 6) * 65 + (i & 63)] = xp[i];
    __syncthreads();
    for (int i = threadIdx.x; i < 1024; i += 256) {
        int h = i >> 5, w = i & 31;
        float a  = xs[(2 * h) * 65 + 2 * w],     bb = xs[(2 * h) * 65 + 2 * w + 1];
        float cc = xs[(2 * h + 1) * 65 + 2 * w], dd = xs[(2 * h + 1) * 65 + 2 * w + 1];
        wt[0][h * 33 + w] = 0.5f * (a + bb + cc + dd);
        wt[1][h * 33 + w] = 0.5f * (a + bb - cc - dd);
        wt[2][h * 33 + w] = 0.5f * (a - bb + cc - dd);
        wt[3][h * 33 + w] = 0.5f * (a - bb - cc + dd);
    }
    __syncthreads();
    float wk[4][9], tb[4];
#pragma unroll
    for (int k = 0; k < 4; ++k) {
        int ch = c * 4 + k;
        float sc = wav_scale[ch];
#pragma unroll
        for (int j = 0; j < 9; ++j) wk[k][j] = wav_w[ch * 9 + j] * sc;
        tb[k] = wav_b[ch] * sc;
    }
    float* upp = up + ((size_t)b * CG + c) * HW;
    for (int i = threadIdx.x; i < 1024; i += 256) {
        int h = i >> 5, w = i & 31;
        float tg[4];
#pragma unroll
        for (int k = 0; k < 4; ++k) {
            float s = tb[k];
#pragma unroll
            for (int dy = -1; dy <= 1; ++dy) {
                int hh = h + dy;
                if (hh < 0 || hh >= 32) continue;
#pragma unroll
                for (int dx = -1; dx <= 1; ++dx) {
                    int wx = w + dx;
                    if (wx < 0 || wx >= 32) continue;
                    s = fmaf(wt[k][hh * 33 + wx], wk[k][(dy + 1) * 3 + (dx + 1)], s);
                }
            }
            tg[k] = s;
        }
        float u00 = 0.5f * (tg[0] - tg[1] - tg[2] + tg[3]);
        float u01 = 0.5f * (tg[0] - tg[1] + tg[2] - tg[3]);
        float u10 = 0.5f * (tg[0] + tg[1] - tg[2] - tg[3]);
        float u11 = 0.5f * (tg[0] + tg[1] + tg[2] + tg[3]);
        upp[(2 * h) * 64 + 2 * w]         = u00;
        upp[(2 * h) * 64 + 2 * w + 1]     = u01;
        upp[(2 * h + 1) * 64 + 2 * w]     = u10;
        upp[(2 * h + 1) * 64 + 2 * w + 1] = u11;
    }
}

// ---------------------------------------------------------------------------
// SS2D input projection: xz = in_w(128x64) @ xg per pixel. Block per (b, h row).
// ---------------------------------------------------------------------------
__global__ __launch_bounds__(256) void k_inproj(const float* __restrict__ x,
                                                const float* __restrict__ in_w,
                                                float* __restrict__ xi,
                                                float* __restrict__ z) {
    int h = blockIdx.x, b = blockIdx.y;
    __shared__ float xs[64 * 65];        // [c][w]
    __shared__ float wl[128 * 64];
    for (int i = threadIdx.x; i < 64 * 64; i += 256) {
        int c = i >> 6, w = i & 63;
        xs[c * 65 + w] = x[((size_t)b * DIM + c) * HW + h * 64 + w];
    }
    for (int i = threadIdx.x; i < 128 * 64; i += 256) wl[i] = in_w[i];
    __syncthreads();
    int lane = threadIdx.x & 63;
    int wave = threadIdx.x >> 6;
    float acc[32];
#pragma unroll
    for (int oi = 0; oi < 32; ++oi) acc[oi] = 0.f;
    for (int c = 0; c < 64; ++c) {
        float xv = xs[c * 65 + lane];
#pragma unroll
        for (int oi = 0; oi < 32; ++oi)
            acc[oi] = fmaf(wl[(wave * 32 + oi) * 64 + c], xv, acc[oi]);
    }
#pragma unroll
    for (int oi = 0; oi < 32; ++oi) {
        int o = wave * 32 + oi;
        float* dst = (o < 64) ? (xi + ((size_t)b * 64 + o) * HW + h * 64)
                              : (z + ((size_t)b * 64 + (o - 64)) * HW + h * 64);
        dst[lane] = acc[oi];
    }
}

// ---------------------------------------------------------------------------
// xc = silu(depthwise3x3(xi) + cb). Block per (b, c) plane.
// ---------------------------------------------------------------------------
__global__ __launch_bounds__(256) void k_dwss(const float* __restrict__ xi,
                                              const float* __restrict__ cw,
                                              const float* __restrict__ cb,
                                              float* __restrict__ xc) {
    int c = blockIdx.x, b = blockIdx.y;
    __shared__ float t[66 * 66];
    const float* p = xi + ((size_t)b * 64 + c) * HW;
    for (int i = threadIdx.x; i < 66 * 66; i += 256) {
        int y = i / 66 - 1, xq = i % 66 - 1;
        t[i] = (y >= 0 && y < 64 && xq >= 0 && xq < 64) ? p[y * 64 + xq] : 0.f;
    }
    __syncthreads();
    float wk[9];
#pragma unroll
    for (int j = 0; j < 9; ++j) wk[j] = cw[c * 9 + j];
    float bias = cb[c];
    float* q = xc + ((size_t)b * 64 + c) * HW;
    for (int i = threadIdx.x; i < HW; i += 256) {
        int y = i >> 6, xq = i & 63;
        float s = bias;
#pragma unroll
        for (int dy = 0; dy < 3; ++dy)
#pragma unroll
            for (int dx = 0; dx < 3; ++dx)
                s = fmaf(t[(y + dy) * 66 + xq + dx], wk[dy * 3 + dx], s);
        q[i] = silu_f(s);
    }
}

// ---------------------------------------------------------------------------
// Per-pixel 6-way projections for both scan directions (dt[4], B, C).
// proj layout: [dir][b][l][8]
// ---------------------------------------------------------------------------
__global__ __launch_bounds__(256) void k_ssproj(const float* __restrict__ xc,
                                                const float* __restrict__ xpw,
                                                float* __restrict__ proj) {
    int h = blockIdx.x, b = blockIdx.y;
    __shared__ float xs[64 * 65];
    for (int i = threadIdx.x; i < 64 * 64; i += 256) {
        int c = i >> 6, w = i & 63;
        xs[c * 65 + w] = xc[((size_t)b * 64 + c) * HW + h * 64 + w];
    }
    __syncthreads();
    int w = threadIdx.x & 63;
    int j = threadIdx.x >> 6;
    for (int m = 0; m < 3; ++m) {
        int pidx = j * 3 + m;
        int dir = pidx / 6, e = pidx % 6;
        float s = 0.f;
        for (int c = 0; c < 64; ++c)
            s = fmaf(xs[c * 65 + w], xpw[(dir * 6 + e) * 64 + c], s);
        int l = (dir == 0) ? (h * 64 + w) : (w * 64 + h);
        proj[(((size_t)dir * NB + b) * HW + l) * 8 + e] = s;
    }
}

// ---------------------------------------------------------------------------
// Selective scan (N=1), segment-compose formulation.
// One wave per (b, dir, d) plane. Lane owns 16 CONTIGUOUS scan elements per
// 1024-element chunk: compose local affine map (A,B); single 6-step cross-lane
// scan per chunk; re-walk applying carry. a/b/C/D*u stay in registers.
// dir=1 output transposed per-chunk through padded LDS -> 64B-aligned stores.
// ---------------------------------------------------------------------------
__global__ __launch_bounds__(256) void k_scan(const float* __restrict__ xc,
                                              const float* __restrict__ proj,
                                              const float* __restrict__ dt_w,
                                              const float* __restrict__ dt_b,
                                              const float* __restrict__ A_log,
                                              const float* __restrict__ Dp,
                                              float* __restrict__ y0,
                                              float* __restrict__ y1) {
    int wave = threadIdx.x >> 6;
    int lane = threadIdx.x & 63;
    int wid = blockIdx.x * 4 + wave;
    int b = wid >> 7;
    int rem = wid & 127;
    int dir = rem >> 6;                  // uniform within a block (4 | 64)
    int d = rem & 63;
    int pd = dir * 64 + d;

    float4 wv = *(const float4*)(dt_w + pd * 4);
    float db = dt_b[pd];
    float A = -expf(A_log[pd]);
    float Dv = Dp[pd];
    const float* pr = proj + ((size_t)dir * NB + b) * HW * 8;
    const float* uplane = xc + ((size_t)b * 64 + d) * HW;
    float* yp = ((dir == 0) ? y0 : y1) + ((size_t)b * 64 + d) * HW;

    __shared__ float lt[4][64 * 17];     // dir=1 transpose tile, padded
    float* myl = lt[wave];

    float carry = 0.f;
    for (int ch = 0; ch < 4; ++ch) {
        int e0 = ch * 1024 + lane * 16;  // first scan index of my segment
        float a[16], bv[16], cm[16], du[16];

        // u loads: dir0 = 16 contiguous floats (4x float4); dir1 = strided
        float uv[16];
        if (dir == 0) {
#pragma unroll
            for (int q = 0; q < 4; ++q) {
                float4 u4 = *(const float4*)(uplane + e0 + q * 4);
                uv[q * 4 + 0] = u4.x; uv[q * 4 + 1] = u4.y;
                uv[q * 4 + 2] = u4.z; uv[q * 4 + 3] = u4.w;
            }
        } else {
            int w_sp = e0 >> 6;          // fixed for all 16 elems of segment
            int h_sp0 = e0 & 63;
#pragma unroll
            for (int j = 0; j < 16; ++j) uv[j] = uplane[(h_sp0 + j) * 64 + w_sp];
        }

        float As = 1.f, Bs = 0.f;
#pragma unroll
        for (int j = 0; j < 16; ++j) {
            const float* pp = pr + (size_t)(e0 + j) * 8;
            float4 p4 = *(const float4*)pp;
            float Bm = pp[4], Cm = pp[5];
            float pre = fmaf(p4.x, wv.x, fmaf(p4.y, wv.y,
                        fmaf(p4.z, wv.z, fmaf(p4.w, wv.w, db))));
            float delta = fmaxf(pre, 0.f) + log1pf(expf(-fabsf(pre)));
            float aj = expf(delta * A);
            float bj = delta * Bm * uv[j];
            a[j] = aj; bv[j] = bj; cm[j] = Cm; du[j] = Dv * uv[j];
            Bs = fmaf(aj, Bs, bj);       // compose segment map
            As *= aj;
        }

        // inclusive cross-lane scan of (As, Bs)
        float Ai = As, Bi = Bs;
#pragma unroll
        for (int off = 1; off < 64; off <<= 1) {
            float ap = __shfl_up(Ai, (unsigned)off, 64);
            float bp = __shfl_up(Bi, (unsigned)off, 64);
            if (lane >= off) { Bi = fmaf(Ai, bp, Bi); Ai *= ap; }
        }
        // h at start of my segment = exclusive prefix applied to chunk carry
        float ap1 = __shfl_up(Ai, 1, 64);
        float bp1 = __shfl_up(Bi, 1, 64);
        float h = (lane == 0) ? carry : fmaf(ap1, carry, bp1);
        // chunk total (lane 63 inclusive) -> next chunk's carry
        float hend = fmaf(Ai, carry, Bi);
        carry = __shfl(hend, 63, 64);

        // apply pass
        float y[16];
#pragma unroll
        for (int j = 0; j < 16; ++j) {
            h = fmaf(a[j], h, bv[j]);
            y[j] = fmaf(h, cm[j], du[j]);
        }

        if (dir == 0) {
            float4* dst = (float4*)(yp + e0);
#pragma unroll
            for (int q = 0; q < 4; ++q)
                dst[q] = make_float4(y[q * 4], y[q * 4 + 1], y[q * 4 + 2], y[q * 4 + 3]);
        } else {
            // scan elem e = lane*16+j -> spatial (h_sp=(lane&3)*16+j, w_local=lane>>2)
            int wl = lane >> 2;
            int hs0 = (lane & 3) * 16;
#pragma unroll
            for (int j = 0; j < 16; ++j) myl[(hs0 + j) * 17 + wl] = y[j];
            __builtin_amdgcn_wave_barrier();   // order LDS writes before reads
            // lane writes spatial row `lane`, cols [ch*16, ch*16+16) -- one 64B line
            int w0 = ch * 16;
            float4* dst = (float4*)(yp + lane * 64 + w0);
#pragma unroll
            for (int q = 0; q < 4; ++q)
                dst[q] = make_float4(myl[lane * 17 + q * 4 + 0],
                                     myl[lane * 17 + q * 4 + 1],
                                     myl[lane * 17 + q * 4 + 2],
                                     myl[lane * 17 + q * 4 + 3]);
            __builtin_amdgcn_wave_barrier();   // keep chunks' LDS uses ordered
        }
    }
}

// ---------------------------------------------------------------------------
// Final: y=(y0+y1)*silu(z); g = ow @ y (1x1 conv); out_g = base_scale*g + up
// ---------------------------------------------------------------------------
__global__ __launch_bounds__(256) void k_final(const float* __restrict__ y0,
                                               const float* __restrict__ y1,
                                               const float* __restrict__ z,
                                               const float* __restrict__ ow,
                                               const float* __restrict__ base_scale,
                                               const float* __restrict__ up,
                                               float* __restrict__ out) {
    int h = blockIdx.x, b = blockIdx.y;
    __shared__ float yv[64 * 65];
    __shared__ float wl[64 * 64];
    for (int i = threadIdx.x; i < 64 * 64; i += 256) {
        int c = i >> 6, w = i & 63;
        size_t idx = ((size_t)b * 64 + c) * HW + h * 64 + w;
        float zz = z[idx];
        yv[c * 65 + w] = (y0[idx] + y1[idx]) * (zz / (1.f + expf(-zz)));
        wl[i] = ow[i];
    }
    __syncthreads();
    for (int i = threadIdx.x; i < 64 * 64; i += 256) {
        int o = i >> 6, w = i & 63;
        float s = 0.f;
        for (int c = 0; c < 64; ++c)
            s = fmaf(wl[o * 64 + c], yv[c * 65 + w], s);
        out[((size_t)b * DIM + o) * HW + h * 64 + w] =
            fmaf(base_scale[o], s, up[((size_t)b * CG + o) * HW + h * 64 + w]);
    }
}

// ---------------------------------------------------------------------------
extern "C" void kernel_launch(void* const* d_in, const int* in_sizes, int n_in,
                              void* d_out, int out_size, void* d_ws, size_t ws_size,
                              hipStream_t stream) {
    (void)in_sizes; (void)n_in; (void)out_size; (void)ws_size;
    const float* x = (const float*)d_in[0];
    float* out = (float*)d_out;
    float* ws = (float*)d_ws;

    const size_t IMG = (size_t)NB * 64 * HW;   // 4,194,304 floats
    float* buf_xi   = ws;                      // reused as y0 after consumption
    float* buf_z    = ws + IMG;
    float* buf_xc   = ws + 2 * IMG;
    float* buf_up   = ws + 3 * IMG;
    float* buf_y1   = ws + 4 * IMG;
    float* buf_proj = ws + 5 * IMG;            // 2*16*4096*8 = 1,048,576 floats
    float* buf_mean = buf_proj + (size_t)2 * NB * HW * 8;  // 1024
    float* buf_w3   = buf_mean + 1024;         // 16*64*9
    float* buf_w5   = buf_w3 + 16 * 64 * 9;    // 16*64*25
    float* buf_w7   = buf_w5 + 16 * 64 * 25;   // 16*64*49

    // ---- local branch ----
    k_mean<<<1024, 256, 0, stream>>>(x, buf_mean);
    k_weff<<<16, 64, 0, stream>>>(buf_mean, (const float*)d_in[1],
                                  (const float*)d_in[2], (const float*)d_in[3], buf_w3, 9);
    k_weff<<<16, 64, 0, stream>>>(buf_mean, (const float*)d_in[8],
                                  (const float*)d_in[9], (const float*)d_in[10], buf_w5, 25);
    k_weff<<<16, 64, 0, stream>>>(buf_mean, (const float*)d_in[15],
                                  (const float*)d_in[16], (const float*)d_in[17], buf_w7, 49);
    k_local<<<dim3(4, 64, 16), 256, 0, stream>>>(x, buf_w3, buf_w5, buf_w7,
        (const float*)d_in[4],  (const float*)d_in[5],  (const float*)d_in[6],  (const float*)d_in[7],
        (const float*)d_in[11], (const float*)d_in[12], (const float*)d_in[13], (const float*)d_in[14],
        (const float*)d_in[18], (const float*)d_in[19], (const float*)d_in[20], (const float*)d_in[21],
        out);

    // ---- wavelet branch (fused dec->conv->rec) ----
    k_up<<<dim3(64, 16), 256, 0, stream>>>(x, (const float*)d_in[22],
        (const float*)d_in[23], (const float*)d_in[24], buf_up);

    // ---- ss2d ----
    k_inproj<<<dim3(64, 16), 256, 0, stream>>>(x, (const float*)d_in[26], buf_xi, buf_z);
    k_dwss<<<dim3(64, 16), 256, 0, stream>>>(buf_xi, (const float*)d_in[27],
        (const float*)d_in[28], buf_xc);
    k_ssproj<<<dim3(64, 16), 256, 0, stream>>>(buf_xc, (const float*)d_in[29], buf_proj);
    k_scan<<<512, 256, 0, stream>>>(buf_xc, buf_proj,
        (const float*)d_in[30], (const float*)d_in[31],
        (const float*)d_in[32], (const float*)d_in[33],
        buf_xi /* y0 (xi is dead now) */, buf_y1);
    k_final<<<dim3(64, 16), 256, 0, stream>>>(buf_xi, buf_y1, buf_z,
        (const float*)d_in[34], (const float*)d_in[25], buf_up, out);

    // ---- passthrough ----
    k_copy_xi<<<(16 * 128 * HW / 4) / 256, 256, 0, stream>>>((const float4*)x, (float4*)out);
}

// Round 3
// 241.307 us; speedup vs baseline: 1.2715x; 1.1497x over previous
//
#include <hip/hip_runtime.h>
#include <math.h>

// Problem constants
static constexpr int NB   = 16;    // batch
static constexpr int DIM  = 256;   // total channels
static constexpr int CG   = 64;    // global-branch channels
static constexpr int HH   = 64;
static constexpr int WW   = 64;
static constexpr int HW   = HH * WW;   // 4096

// mish(x) = x*tanh(softplus(x)) = x*(t^2+2t)/(t^2+2t+2), t=e^x.
// Clamp at 20: for x>=20 the ratio is 1.0 in fp32 exactly.
__device__ __forceinline__ float mish_fast(float x) {
    float t = __expf(fminf(x, 20.f));
    float p = __builtin_fmaf(t, t, t + t);         // t^2 + 2t
    return x * p * __builtin_amdgcn_rcpf(p + 2.f);
}
__device__ __forceinline__ float silu_f(float x) {
    return x * __builtin_amdgcn_rcpf(1.f + __expf(-x));
}

// ---------------------------------------------------------------------------
// Passthrough: out[:,128:256] = x[:,128:256]   (identical flat indices)
// ---------------------------------------------------------------------------
__global__ __launch_bounds__(256) void k_copy_xi(const float4* __restrict__ x,
                                                 float4* __restrict__ out) {
    int i = blockIdx.x * 256 + threadIdx.x;            // 16*128*1024 float4
    const int per_b = 128 * HW / 4;                    // 131072
    int b = i / per_b, r = i % per_b;
    int idx = b * (DIM * HW / 4) + per_b + r;
    out[idx] = x[idx];
}

// ---------------------------------------------------------------------------
// Local branch: per-(b,c) channel mean of xl
// ---------------------------------------------------------------------------
__global__ __launch_bounds__(256) void k_mean(const float* __restrict__ x,
                                              float* __restrict__ mean) {
    int bc = blockIdx.x;                 // b*64 + c
    int b = bc >> 6, c = bc & 63;
    const float* p = x + ((size_t)b * DIM + 64 + c) * HW;
    float s = 0.f;
    for (int i = threadIdx.x; i < HW; i += 256) s += p[i];
    __shared__ float red[256];
    red[threadIdx.x] = s;
    __syncthreads();
    for (int o = 128; o > 0; o >>= 1) {
        if (threadIdx.x < o) red[threadIdx.x] += red[threadIdx.x + o];
        __syncthreads();
    }
    if (threadIdx.x == 0) mean[bc] = red[0] * (1.f / HW);
}

// ---------------------------------------------------------------------------
// gates = softmax(mean @ gw.T); weff[b,c,:] = (sum_e g_e * ew[e,c]) * bn1scale
// ---------------------------------------------------------------------------
__global__ void k_weff(const float* __restrict__ mean,
                       const float* __restrict__ ew,
                       const float* __restrict__ gw,
                       const float* __restrict__ bn1g,
                       float* __restrict__ weff, int k2) {
    int b = blockIdx.x;
    int c = threadIdx.x;                 // 64 threads
    __shared__ float m[64];
    __shared__ float g[4];
    m[c] = mean[b * 64 + c];
    __syncthreads();
    if (c < 4) {
        float l = 0.f;
        for (int cc = 0; cc < 64; ++cc) l += m[cc] * gw[c * 64 + cc];
        g[c] = l;
    }
    __syncthreads();
    if (c == 0) {
        float mx = fmaxf(fmaxf(g[0], g[1]), fmaxf(g[2], g[3]));
        float e0 = expf(g[0] - mx), e1 = expf(g[1] - mx);
        float e2 = expf(g[2] - mx), e3 = expf(g[3] - mx);
        float inv = 1.f / (e0 + e1 + e2 + e3);
        g[0] = e0 * inv; g[1] = e1 * inv; g[2] = e2 * inv; g[3] = e3 * inv;
    }
    __syncthreads();
    float g1s = bn1g[c] * rsqrtf(1.f + 1e-5f);
    for (int kk = 0; kk < k2; ++kk) {
        float w = 0.f;
        for (int e = 0; e < 4; ++e) w += g[e] * ew[(e * 64 + c) * k2 + kk];
        weff[(b * 64 + c) * k2 + kk] = w * g1s;
    }
}

// ---------------------------------------------------------------------------
// Local branch conv v2: register-blocked. Each lane owns a 4-wide x strip.
// Per dy: 3x ds_read_b128 row load (12 floats) shared by the 3x3/5x5/7x7 taps.
// Weights via block-uniform global reads -> SGPRs.
// ---------------------------------------------------------------------------
__global__ __launch_bounds__(256) void k_local(
    const float* __restrict__ x,
    const float* __restrict__ w3, const float* __restrict__ w5, const float* __restrict__ w7,
    const float* __restrict__ b1_0, const float* __restrict__ pw0,
    const float* __restrict__ g2_0, const float* __restrict__ b2_0,
    const float* __restrict__ b1_1, const float* __restrict__ pw1,
    const float* __restrict__ g2_1, const float* __restrict__ b2_1,
    const float* __restrict__ b1_2, const float* __restrict__ pw2,
    const float* __restrict__ g2_2, const float* __restrict__ b2_2,
    float* __restrict__ out) {
    int tile = blockIdx.x;               // 0..3
    int c = blockIdx.y, b = blockIdx.z;
    int oy = (tile >> 1) * 32, ox = (tile & 1) * 32;
    __shared__ float t[38 * 40];         // row stride 40 floats = 160B (16B-aligned)
    const float* xp = x + ((size_t)b * DIM + 64 + c) * HW;
    for (int i = threadIdx.x; i < 38 * 38; i += 256) {
        int r = i / 38, cc = i % 38;
        int yy = r - 3 + oy, xx = cc - 3 + ox;
        t[r * 40 + cc] = (yy >= 0 && yy < 64 && xx >= 0 && xx < 64) ? xp[yy * 64 + xx] : 0.f;
    }
    // Block-uniform weight loads -> scalar registers
    const float* w3p = w3 + (b * 64 + c) * 9;
    const float* w5p = w5 + (b * 64 + c) * 25;
    const float* w7p = w7 + (b * 64 + c) * 49;
    float W3r[9], W5r[25], W7r[49];
#pragma unroll
    for (int j = 0; j < 9; ++j)  W3r[j] = w3p[j];
#pragma unroll
    for (int j = 0; j < 25; ++j) W5r[j] = w5p[j];
#pragma unroll
    for (int j = 0; j < 49; ++j) W7r[j] = w7p[j];
    __syncthreads();

    const float rs = rsqrtf(1.f + 1e-5f);
    float bb1a = b1_0[c], bb1b = b1_1[c], bb1c = b1_2[c];
    float ssa = pw0[c] * g2_0[c] * rs, ssb = pw1[c] * g2_1[c] * rs, ssc = pw2[c] * g2_2[c] * rs;
    float bb2a = b2_0[c], bb2b = b2_1[c], bb2c = b2_2[c];

    int y  = threadIdx.x >> 3;           // 0..31
    int x0 = (threadIdx.x & 7) * 4;      // 0,4,...,28

    float a3[4] = {0.f, 0.f, 0.f, 0.f};
    float a5[4] = {0.f, 0.f, 0.f, 0.f};
    float a7[4] = {0.f, 0.f, 0.f, 0.f};

#pragma unroll
    for (int dy = 0; dy < 7; ++dy) {
        const float4* rp = (const float4*)(t + (y + dy) * 40 + x0);
        float4 q0 = rp[0], q1 = rp[1], q2 = rp[2];
        float r[12] = {q0.x, q0.y, q0.z, q0.w, q1.x, q1.y, q1.z, q1.w,
                       q2.x, q2.y, q2.z, q2.w};
#pragma unroll
        for (int k = 0; k < 4; ++k)
#pragma unroll
            for (int dx = 0; dx < 7; ++dx)
                a7[k] = fmaf(r[k + dx], W7r[dy * 7 + dx], a7[k]);
        if (dy >= 1 && dy <= 5) {
            int ey = dy - 1;
#pragma unroll
            for (int k = 0; k < 4; ++k)
#pragma unroll
                for (int dx = 0; dx < 5; ++dx)
                    a5[k] = fmaf(r[k + 1 + dx], W5r[ey * 5 + dx], a5[k]);
        }
        if (dy >= 2 && dy <= 4) {
            int ey = dy - 2;
#pragma unroll
            for (int k = 0; k < 4; ++k)
#pragma unroll
                for (int dx = 0; dx < 3; ++dx)
                    a3[k] = fmaf(r[k + 2 + dx], W3r[ey * 3 + dx], a3[k]);
        }
    }

    float4 res;
    float* rr = (float*)&res;
#pragma unroll
    for (int k = 0; k < 4; ++k) {
        rr[k] = mish_fast(a3[k] + bb1a) * ssa + bb2a
              + mish_fast(a5[k] + bb1b) * ssb + bb2b
              + mish_fast(a7[k] + bb1c) * ssc + bb2c;
    }
    float* op = out + ((size_t)b * DIM + 64 + c) * HW;
    *(float4*)(op + (oy + y) * 64 + ox + x0) = res;
}

// ---------------------------------------------------------------------------
// Fused wavelet: Haar decompose -> depthwise 3x3 conv + bias, *scale -> Haar rec.
// One block per (b, c): full 64x64 plane in LDS.
// ---------------------------------------------------------------------------
__global__ __launch_bounds__(256) void k_up(const float* __restrict__ x,
                                            const float* __restrict__ wav_w,
                                            const float* __restrict__ wav_b,
                                            const float* __restrict__ wav_scale,
                                            float* __restrict__ up) {
    int c = blockIdx.x, b = blockIdx.y;
    __shared__ float xs[64 * 65];
    __shared__ float wt[4][32 * 33];
    const float* xp = x + ((size_t)b * DIM + c) * HW;
    for (int i = threadIdx.x; i < HW; i += 256) xs[(i >> 6) * 65 + (i & 63)] = xp[i];
    __syncthreads();
    for (int i = threadIdx.x; i < 1024; i += 256) {
        int h = i >> 5, w = i & 31;
        float a  = xs[(2 * h) * 65 + 2 * w],     bb = xs[(2 * h) * 65 + 2 * w + 1];
        float cc = xs[(2 * h + 1) * 65 + 2 * w], dd = xs[(2 * h + 1) * 65 + 2 * w + 1];
        wt[0][h * 33 + w] = 0.5f * (a + bb + cc + dd);
        wt[1][h * 33 + w] = 0.5f * (a + bb - cc - dd);
        wt[2][h * 33 + w] = 0.5f * (a - bb + cc - dd);
        wt[3][h * 33 + w] = 0.5f * (a - bb - cc + dd);
    }
    __syncthreads();
    float wk[4][9], tb[4];
#pragma unroll
    for (int k = 0; k < 4; ++k) {
        int ch = c * 4 + k;
        float sc = wav_scale[ch];
#pragma unroll
        for (int j = 0; j < 9; ++j) wk[k][j] = wav_w[ch * 9 + j] * sc;
        tb[k] = wav_b[ch] * sc;
    }
    float* upp = up + ((size_t)b * CG + c) * HW;
    for (int i = threadIdx.x; i < 1024; i += 256) {
        int h = i >> 5, w = i & 31;
        float tg[4];
#pragma unroll
        for (int k = 0; k < 4; ++k) {
            float s = tb[k];
#pragma unroll
            for (int dy = -1; dy <= 1; ++dy) {
                int hh = h + dy;
                if (hh < 0 || hh >= 32) continue;
#pragma unroll
                for (int dx = -1; dx <= 1; ++dx) {
                    int wx = w + dx;
                    if (wx < 0 || wx >= 32) continue;
                    s = fmaf(wt[k][hh * 33 + wx], wk[k][(dy + 1) * 3 + (dx + 1)], s);
                }
            }
            tg[k] = s;
        }
        float u00 = 0.5f * (tg[0] - tg[1] - tg[2] + tg[3]);
        float u01 = 0.5f * (tg[0] - tg[1] + tg[2] - tg[3]);
        float u10 = 0.5f * (tg[0] + tg[1] - tg[2] - tg[3]);
        float u11 = 0.5f * (tg[0] + tg[1] + tg[2] + tg[3]);
        upp[(2 * h) * 64 + 2 * w]         = u00;
        upp[(2 * h) * 64 + 2 * w + 1]     = u01;
        upp[(2 * h + 1) * 64 + 2 * w]     = u10;
        upp[(2 * h + 1) * 64 + 2 * w + 1] = u11;
    }
}

// ---------------------------------------------------------------------------
// SS2D input projection: xz = in_w(128x64) @ xg per pixel. Block per (b, h row).
// ---------------------------------------------------------------------------
__global__ __launch_bounds__(256) void k_inproj(const float* __restrict__ x,
                                                const float* __restrict__ in_w,
                                                float* __restrict__ xi,
                                                float* __restrict__ z) {
    int h = blockIdx.x, b = blockIdx.y;
    __shared__ float xs[64 * 65];        // [c][w]
    __shared__ float wl[128 * 64];
    for (int i = threadIdx.x; i < 64 * 64; i += 256) {
        int c = i >> 6, w = i & 63;
        xs[c * 65 + w] = x[((size_t)b * DIM + c) * HW + h * 64 + w];
    }
    for (int i = threadIdx.x; i < 128 * 64; i += 256) wl[i] = in_w[i];
    __syncthreads();
    int lane = threadIdx.x & 63;
    int wave = threadIdx.x >> 6;
    float acc[32];
#pragma unroll
    for (int oi = 0; oi < 32; ++oi) acc[oi] = 0.f;
    for (int c = 0; c < 64; ++c) {
        float xv = xs[c * 65 + lane];
#pragma unroll
        for (int oi = 0; oi < 32; ++oi)
            acc[oi] = fmaf(wl[(wave * 32 + oi) * 64 + c], xv, acc[oi]);
    }
#pragma unroll
    for (int oi = 0; oi < 32; ++oi) {
        int o = wave * 32 + oi;
        float* dst = (o < 64) ? (xi + ((size_t)b * 64 + o) * HW + h * 64)
                              : (z + ((size_t)b * 64 + (o - 64)) * HW + h * 64);
        dst[lane] = acc[oi];
    }
}

// ---------------------------------------------------------------------------
// xc = silu(depthwise3x3(xi) + cb). Block per (b, c) plane.
// ---------------------------------------------------------------------------
__global__ __launch_bounds__(256) void k_dwss(const float* __restrict__ xi,
                                              const float* __restrict__ cw,
                                              const float* __restrict__ cb,
                                              float* __restrict__ xc) {
    int c = blockIdx.x, b = blockIdx.y;
    __shared__ float t[66 * 66];
    const float* p = xi + ((size_t)b * 64 + c) * HW;
    for (int i = threadIdx.x; i < 66 * 66; i += 256) {
        int y = i / 66 - 1, xq = i % 66 - 1;
        t[i] = (y >= 0 && y < 64 && xq >= 0 && xq < 64) ? p[y * 64 + xq] : 0.f;
    }
    __syncthreads();
    float wk[9];
#pragma unroll
    for (int j = 0; j < 9; ++j) wk[j] = cw[c * 9 + j];
    float bias = cb[c];
    float* q = xc + ((size_t)b * 64 + c) * HW;
    for (int i = threadIdx.x; i < HW; i += 256) {
        int y = i >> 6, xq = i & 63;
        float s = bias;
#pragma unroll
        for (int dy = 0; dy < 3; ++dy)
#pragma unroll
            for (int dx = 0; dx < 3; ++dx)
                s = fmaf(t[(y + dy) * 66 + xq + dx], wk[dy * 3 + dx], s);
        q[i] = silu_f(s);
    }
}

// ---------------------------------------------------------------------------
// Per-pixel 6-way projections for both scan directions (dt[4], B, C).
// proj layout: [dir][b][l][8]
// ---------------------------------------------------------------------------
__global__ __launch_bounds__(256) void k_ssproj(const float* __restrict__ xc,
                                                const float* __restrict__ xpw,
                                                float* __restrict__ proj) {
    int h = blockIdx.x, b = blockIdx.y;
    __shared__ float xs[64 * 65];
    for (int i = threadIdx.x; i < 64 * 64; i += 256) {
        int c = i >> 6, w = i & 63;
        xs[c * 65 + w] = xc[((size_t)b * 64 + c) * HW + h * 64 + w];
    }
    __syncthreads();
    int w = threadIdx.x & 63;
    int j = threadIdx.x >> 6;
    for (int m = 0; m < 3; ++m) {
        int pidx = j * 3 + m;
        int dir = pidx / 6, e = pidx % 6;
        float s = 0.f;
        for (int c = 0; c < 64; ++c)
            s = fmaf(xs[c * 65 + w], xpw[(dir * 6 + e) * 64 + c], s);
        int l = (dir == 0) ? (h * 64 + w) : (w * 64 + h);
        proj[(((size_t)dir * NB + b) * HW + l) * 8 + e] = s;
    }
}

// ---------------------------------------------------------------------------
// Selective scan (N=1), segment-compose formulation.
// ---------------------------------------------------------------------------
__global__ __launch_bounds__(256) void k_scan(const float* __restrict__ xc,
                                              const float* __restrict__ proj,
                                              const float* __restrict__ dt_w,
                                              const float* __restrict__ dt_b,
                                              const float* __restrict__ A_log,
                                              const float* __restrict__ Dp,
                                              float* __restrict__ y0,
                                              float* __restrict__ y1) {
    int wave = threadIdx.x >> 6;
    int lane = threadIdx.x & 63;
    int wid = blockIdx.x * 4 + wave;
    int b = wid >> 7;
    int rem = wid & 127;
    int dir = rem >> 6;                  // uniform within a block (4 | 64)
    int d = rem & 63;
    int pd = dir * 64 + d;

    float4 wv = *(const float4*)(dt_w + pd * 4);
    float db = dt_b[pd];
    float A = -expf(A_log[pd]);
    float Dv = Dp[pd];
    const float* pr = proj + ((size_t)dir * NB + b) * HW * 8;
    const float* uplane = xc + ((size_t)b * 64 + d) * HW;
    float* yp = ((dir == 0) ? y0 : y1) + ((size_t)b * 64 + d) * HW;

    __shared__ float lt[4][64 * 17];     // dir=1 transpose tile, padded
    float* myl = lt[wave];

    float carry = 0.f;
    for (int ch = 0; ch < 4; ++ch) {
        int e0 = ch * 1024 + lane * 16;  // first scan index of my segment
        float a[16], bv[16], cm[16], du[16];

        float uv[16];
        if (dir == 0) {
#pragma unroll
            for (int q = 0; q < 4; ++q) {
                float4 u4 = *(const float4*)(uplane + e0 + q * 4);
                uv[q * 4 + 0] = u4.x; uv[q * 4 + 1] = u4.y;
                uv[q * 4 + 2] = u4.z; uv[q * 4 + 3] = u4.w;
            }
        } else {
            int w_sp = e0 >> 6;          // fixed for all 16 elems of segment
            int h_sp0 = e0 & 63;
#pragma unroll
            for (int j = 0; j < 16; ++j) uv[j] = uplane[(h_sp0 + j) * 64 + w_sp];
        }

        float As = 1.f, Bs = 0.f;
#pragma unroll
        for (int j = 0; j < 16; ++j) {
            const float* pp = pr + (size_t)(e0 + j) * 8;
            float4 p4 = *(const float4*)pp;
            float Bm = pp[4], Cm = pp[5];
            float pre = fmaf(p4.x, wv.x, fmaf(p4.y, wv.y,
                        fmaf(p4.z, wv.z, fmaf(p4.w, wv.w, db))));
            float delta = fmaxf(pre, 0.f) + log1pf(expf(-fabsf(pre)));
            float aj = expf(delta * A);
            float bj = delta * Bm * uv[j];
            a[j] = aj; bv[j] = bj; cm[j] = Cm; du[j] = Dv * uv[j];
            Bs = fmaf(aj, Bs, bj);       // compose segment map
            As *= aj;
        }

        // inclusive cross-lane scan of (As, Bs)
        float Ai = As, Bi = Bs;
#pragma unroll
        for (int off = 1; off < 64; off <<= 1) {
            float ap = __shfl_up(Ai, (unsigned)off, 64);
            float bp = __shfl_up(Bi, (unsigned)off, 64);
            if (lane >= off) { Bi = fmaf(Ai, bp, Bi); Ai *= ap; }
        }
        float ap1 = __shfl_up(Ai, 1, 64);
        float bp1 = __shfl_up(Bi, 1, 64);
        float h = (lane == 0) ? carry : fmaf(ap1, carry, bp1);
        float hend = fmaf(Ai, carry, Bi);
        carry = __shfl(hend, 63, 64);

        float y[16];
#pragma unroll
        for (int j = 0; j < 16; ++j) {
            h = fmaf(a[j], h, bv[j]);
            y[j] = fmaf(h, cm[j], du[j]);
        }

        if (dir == 0) {
            float4* dst = (float4*)(yp + e0);
#pragma unroll
            for (int q = 0; q < 4; ++q)
                dst[q] = make_float4(y[q * 4], y[q * 4 + 1], y[q * 4 + 2], y[q * 4 + 3]);
        } else {
            int wl = lane >> 2;
            int hs0 = (lane & 3) * 16;
#pragma unroll
            for (int j = 0; j < 16; ++j) myl[(hs0 + j) * 17 + wl] = y[j];
            __builtin_amdgcn_wave_barrier();
            int w0 = ch * 16;
            float4* dst = (float4*)(yp + lane * 64 + w0);
#pragma unroll
            for (int q = 0; q < 4; ++q)
                dst[q] = make_float4(myl[lane * 17 + q * 4 + 0],
                                     myl[lane * 17 + q * 4 + 1],
                                     myl[lane * 17 + q * 4 + 2],
                                     myl[lane * 17 + q * 4 + 3]);
            __builtin_amdgcn_wave_barrier();
        }
    }
}

// ---------------------------------------------------------------------------
// Final: y=(y0+y1)*silu(z); g = ow @ y (1x1 conv); out_g = base_scale*g + up
// ---------------------------------------------------------------------------
__global__ __launch_bounds__(256) void k_final(const float* __restrict__ y0,
                                               const float* __restrict__ y1,
                                               const float* __restrict__ z,
                                               const float* __restrict__ ow,
                                               const float* __restrict__ base_scale,
                                               const float* __restrict__ up,
                                               float* __restrict__ out) {
    int h = blockIdx.x, b = blockIdx.y;
    __shared__ float yv[64 * 65];
    __shared__ float wl[64 * 64];
    for (int i = threadIdx.x; i < 64 * 64; i += 256) {
        int c = i >> 6, w = i & 63;
        size_t idx = ((size_t)b * 64 + c) * HW + h * 64 + w;
        float zz = z[idx];
        yv[c * 65 + w] = (y0[idx] + y1[idx]) * silu_f(zz);
        wl[i] = ow[i];
    }
    __syncthreads();
    for (int i = threadIdx.x; i < 64 * 64; i += 256) {
        int o = i >> 6, w = i & 63;
        float s = 0.f;
        for (int c = 0; c < 64; ++c)
            s = fmaf(wl[o * 64 + c], yv[c * 65 + w], s);
        out[((size_t)b * DIM + o) * HW + h * 64 + w] =
            fmaf(base_scale[o], s, up[((size_t)b * CG + o) * HW + h * 64 + w]);
    }
}

// ---------------------------------------------------------------------------
extern "C" void kernel_launch(void* const* d_in, const int* in_sizes, int n_in,
                              void* d_out, int out_size, void* d_ws, size_t ws_size,
                              hipStream_t stream) {
    (void)in_sizes; (void)n_in; (void)out_size; (void)ws_size;
    const float* x = (const float*)d_in[0];
    float* out = (float*)d_out;
    float* ws = (float*)d_ws;

    const size_t IMG = (size_t)NB * 64 * HW;   // 4,194,304 floats
    float* buf_xi   = ws;                      // reused as y0 after consumption
    float* buf_z    = ws + IMG;
    float* buf_xc   = ws + 2 * IMG;
    float* buf_up   = ws + 3 * IMG;
    float* buf_y1   = ws + 4 * IMG;
    float* buf_proj = ws + 5 * IMG;            // 2*16*4096*8 = 1,048,576 floats
    float* buf_mean = buf_proj + (size_t)2 * NB * HW * 8;  // 1024
    float* buf_w3   = buf_mean + 1024;         // 16*64*9
    float* buf_w5   = buf_w3 + 16 * 64 * 9;    // 16*64*25
    float* buf_w7   = buf_w5 + 16 * 64 * 25;   // 16*64*49

    // ---- local branch ----
    k_mean<<<1024, 256, 0, stream>>>(x, buf_mean);
    k_weff<<<16, 64, 0, stream>>>(buf_mean, (const float*)d_in[1],
                                  (const float*)d_in[2], (const float*)d_in[3], buf_w3, 9);
    k_weff<<<16, 64, 0, stream>>>(buf_mean, (const float*)d_in[8],
                                  (const float*)d_in[9], (const float*)d_in[10], buf_w5, 25);
    k_weff<<<16, 64, 0, stream>>>(buf_mean, (const float*)d_in[15],
                                  (const float*)d_in[16], (const float*)d_in[17], buf_w7, 49);
    k_local<<<dim3(4, 64, 16), 256, 0, stream>>>(x, buf_w3, buf_w5, buf_w7,
        (const float*)d_in[4],  (const float*)d_in[5],  (const float*)d_in[6],  (const float*)d_in[7],
        (const float*)d_in[11], (const float*)d_in[12], (const float*)d_in[13], (const float*)d_in[14],
        (const float*)d_in[18], (const float*)d_in[19], (const float*)d_in[20], (const float*)d_in[21],
        out);

    // ---- wavelet branch (fused dec->conv->rec) ----
    k_up<<<dim3(64, 16), 256, 0, stream>>>(x, (const float*)d_in[22],
        (const float*)d_in[23], (const float*)d_in[24], buf_up);

    // ---- ss2d ----
    k_inproj<<<dim3(64, 16), 256, 0, stream>>>(x, (const float*)d_in[26], buf_xi, buf_z);
    k_dwss<<<dim3(64, 16), 256, 0, stream>>>(buf_xi, (const float*)d_in[27],
        (const float*)d_in[28], buf_xc);
    k_ssproj<<<dim3(64, 16), 256, 0, stream>>>(buf_xc, (const float*)d_in[29], buf_proj);
    k_scan<<<512, 256, 0, stream>>>(buf_xc, buf_proj,
        (const float*)d_in[30], (const float*)d_in[31],
        (const float*)d_in[32], (const float*)d_in[33],
        buf_xi /* y0 (xi is dead now) */, buf_y1);
    k_final<<<dim3(64, 16), 256, 0, stream>>>(buf_xi, buf_y1, buf_z,
        (const float*)d_in[34], (const float*)d_in[25], buf_up, out);

    // ---- passthrough ----
    k_copy_xi<<<(16 * 128 * HW / 4) / 256, 256, 0, stream>>>((const float4*)x, (float4*)out);
}

// Round 4
// 231.989 us; speedup vs baseline: 1.3225x; 1.0402x over previous
//
#include <hip/hip_runtime.h>
#include <math.h>

// Problem constants
static constexpr int NB   = 16;    // batch
static constexpr int DIM  = 256;   // total channels
static constexpr int CG   = 64;    // global-branch channels
static constexpr int HH   = 64;
static constexpr int WW   = 64;
static constexpr int HW   = HH * WW;   // 4096

// mish(x) = x*tanh(softplus(x)) = x*(t^2+2t)/(t^2+2t+2), t=e^x.
// Clamp at 20: for x>=20 the ratio is 1.0 in fp32 exactly.
__device__ __forceinline__ float mish_fast(float x) {
    float t = __expf(fminf(x, 20.f));
    float p = __builtin_fmaf(t, t, t + t);         // t^2 + 2t
    return x * p * __builtin_amdgcn_rcpf(p + 2.f);
}
__device__ __forceinline__ float silu_f(float x) {
    return x * __builtin_amdgcn_rcpf(1.f + __expf(-x));
}
// softplus via hw exp/log: max(x,0) + log(1 + e^-|x|). Error vs log1pf < 2 ulp.
__device__ __forceinline__ float softplus_fast(float x) {
    return fmaxf(x, 0.f) + __logf(1.f + __expf(-fabsf(x)));
}

// ---------------------------------------------------------------------------
// Passthrough: out[:,128:256] = x[:,128:256]   (identical flat indices)
// ---------------------------------------------------------------------------
__global__ __launch_bounds__(256) void k_copy_xi(const float4* __restrict__ x,
                                                 float4* __restrict__ out) {
    int i = blockIdx.x * 256 + threadIdx.x;            // 16*128*1024 float4
    const int per_b = 128 * HW / 4;                    // 131072
    int b = i / per_b, r = i % per_b;
    int idx = b * (DIM * HW / 4) + per_b + r;
    out[idx] = x[idx];
}

// ---------------------------------------------------------------------------
// Local branch: per-(b,c) channel mean of xl
// ---------------------------------------------------------------------------
__global__ __launch_bounds__(256) void k_mean(const float* __restrict__ x,
                                              float* __restrict__ mean) {
    int bc = blockIdx.x;                 // b*64 + c
    int b = bc >> 6, c = bc & 63;
    const float* p = x + ((size_t)b * DIM + 64 + c) * HW;
    float s = 0.f;
    for (int i = threadIdx.x; i < HW; i += 256) s += p[i];
    __shared__ float red[256];
    red[threadIdx.x] = s;
    __syncthreads();
    for (int o = 128; o > 0; o >>= 1) {
        if (threadIdx.x < o) red[threadIdx.x] += red[threadIdx.x + o];
        __syncthreads();
    }
    if (threadIdx.x == 0) mean[bc] = red[0] * (1.f / HW);
}

// ---------------------------------------------------------------------------
// gates = softmax(mean @ gw.T); weff[b,c,:] = (sum_e g_e * ew[e,c]) * bn1scale
// ---------------------------------------------------------------------------
__global__ void k_weff(const float* __restrict__ mean,
                       const float* __restrict__ ew,
                       const float* __restrict__ gw,
                       const float* __restrict__ bn1g,
                       float* __restrict__ weff, int k2) {
    int b = blockIdx.x;
    int c = threadIdx.x;                 // 64 threads
    __shared__ float m[64];
    __shared__ float g[4];
    m[c] = mean[b * 64 + c];
    __syncthreads();
    if (c < 4) {
        float l = 0.f;
        for (int cc = 0; cc < 64; ++cc) l += m[cc] * gw[c * 64 + cc];
        g[c] = l;
    }
    __syncthreads();
    if (c == 0) {
        float mx = fmaxf(fmaxf(g[0], g[1]), fmaxf(g[2], g[3]));
        float e0 = expf(g[0] - mx), e1 = expf(g[1] - mx);
        float e2 = expf(g[2] - mx), e3 = expf(g[3] - mx);
        float inv = 1.f / (e0 + e1 + e2 + e3);
        g[0] = e0 * inv; g[1] = e1 * inv; g[2] = e2 * inv; g[3] = e3 * inv;
    }
    __syncthreads();
    float g1s = bn1g[c] * rsqrtf(1.f + 1e-5f);
    for (int kk = 0; kk < k2; ++kk) {
        float w = 0.f;
        for (int e = 0; e < 4; ++e) w += g[e] * ew[(e * 64 + c) * k2 + kk];
        weff[(b * 64 + c) * k2 + kk] = w * g1s;
    }
}

// ---------------------------------------------------------------------------
// Local branch conv v2: register-blocked. Each lane owns a 4-wide x strip.
// Per dy: 3x ds_read_b128 row load (12 floats) shared by the 3x3/5x5/7x7 taps.
// Weights via block-uniform global reads -> SGPRs.
// ---------------------------------------------------------------------------
__global__ __launch_bounds__(256) void k_local(
    const float* __restrict__ x,
    const float* __restrict__ w3, const float* __restrict__ w5, const float* __restrict__ w7,
    const float* __restrict__ b1_0, const float* __restrict__ pw0,
    const float* __restrict__ g2_0, const float* __restrict__ b2_0,
    const float* __restrict__ b1_1, const float* __restrict__ pw1,
    const float* __restrict__ g2_1, const float* __restrict__ b2_1,
    const float* __restrict__ b1_2, const float* __restrict__ pw2,
    const float* __restrict__ g2_2, const float* __restrict__ b2_2,
    float* __restrict__ out) {
    int tile = blockIdx.x;               // 0..3
    int c = blockIdx.y, b = blockIdx.z;
    int oy = (tile >> 1) * 32, ox = (tile & 1) * 32;
    __shared__ float t[38 * 40];         // row stride 40 floats = 160B (16B-aligned)
    const float* xp = x + ((size_t)b * DIM + 64 + c) * HW;
    for (int i = threadIdx.x; i < 38 * 38; i += 256) {
        int r = i / 38, cc = i % 38;
        int yy = r - 3 + oy, xx = cc - 3 + ox;
        t[r * 40 + cc] = (yy >= 0 && yy < 64 && xx >= 0 && xx < 64) ? xp[yy * 64 + xx] : 0.f;
    }
    // Block-uniform weight loads -> scalar registers
    const float* w3p = w3 + (b * 64 + c) * 9;
    const float* w5p = w5 + (b * 64 + c) * 25;
    const float* w7p = w7 + (b * 64 + c) * 49;
    float W3r[9], W5r[25], W7r[49];
#pragma unroll
    for (int j = 0; j < 9; ++j)  W3r[j] = w3p[j];
#pragma unroll
    for (int j = 0; j < 25; ++j) W5r[j] = w5p[j];
#pragma unroll
    for (int j = 0; j < 49; ++j) W7r[j] = w7p[j];
    __syncthreads();

    const float rs = rsqrtf(1.f + 1e-5f);
    float bb1a = b1_0[c], bb1b = b1_1[c], bb1c = b1_2[c];
    float ssa = pw0[c] * g2_0[c] * rs, ssb = pw1[c] * g2_1[c] * rs, ssc = pw2[c] * g2_2[c] * rs;
    float bb2a = b2_0[c], bb2b = b2_1[c], bb2c = b2_2[c];

    int y  = threadIdx.x >> 3;           // 0..31
    int x0 = (threadIdx.x & 7) * 4;      // 0,4,...,28

    float a3[4] = {0.f, 0.f, 0.f, 0.f};
    float a5[4] = {0.f, 0.f, 0.f, 0.f};
    float a7[4] = {0.f, 0.f, 0.f, 0.f};

#pragma unroll
    for (int dy = 0; dy < 7; ++dy) {
        const float4* rp = (const float4*)(t + (y + dy) * 40 + x0);
        float4 q0 = rp[0], q1 = rp[1], q2 = rp[2];
        float r[12] = {q0.x, q0.y, q0.z, q0.w, q1.x, q1.y, q1.z, q1.w,
                       q2.x, q2.y, q2.z, q2.w};
#pragma unroll
        for (int k = 0; k < 4; ++k)
#pragma unroll
            for (int dx = 0; dx < 7; ++dx)
                a7[k] = fmaf(r[k + dx], W7r[dy * 7 + dx], a7[k]);
        if (dy >= 1 && dy <= 5) {
            int ey = dy - 1;
#pragma unroll
            for (int k = 0; k < 4; ++k)
#pragma unroll
                for (int dx = 0; dx < 5; ++dx)
                    a5[k] = fmaf(r[k + 1 + dx], W5r[ey * 5 + dx], a5[k]);
        }
        if (dy >= 2 && dy <= 4) {
            int ey = dy - 2;
#pragma unroll
            for (int k = 0; k < 4; ++k)
#pragma unroll
                for (int dx = 0; dx < 3; ++dx)
                    a3[k] = fmaf(r[k + 2 + dx], W3r[ey * 3 + dx], a3[k]);
        }
    }

    float4 res;
    float* rr = (float*)&res;
#pragma unroll
    for (int k = 0; k < 4; ++k) {
        rr[k] = mish_fast(a3[k] + bb1a) * ssa + bb2a
              + mish_fast(a5[k] + bb1b) * ssb + bb2b
              + mish_fast(a7[k] + bb1c) * ssc + bb2c;
    }
    float* op = out + ((size_t)b * DIM + 64 + c) * HW;
    *(float4*)(op + (oy + y) * 64 + ox + x0) = res;
}

// ---------------------------------------------------------------------------
// Fused wavelet: Haar decompose -> depthwise 3x3 conv + bias, *scale -> Haar rec.
// One block per (b, c): full 64x64 plane in LDS.
// ---------------------------------------------------------------------------
__global__ __launch_bounds__(256) void k_up(const float* __restrict__ x,
                                            const float* __restrict__ wav_w,
                                            const float* __restrict__ wav_b,
                                            const float* __restrict__ wav_scale,
                                            float* __restrict__ up) {
    int c = blockIdx.x, b = blockIdx.y;
    __shared__ float xs[64 * 65];
    __shared__ float wt[4][32 * 33];
    const float* xp = x + ((size_t)b * DIM + c) * HW;
    for (int i = threadIdx.x; i < HW; i += 256) xs[(i >> 6) * 65 + (i & 63)] = xp[i];
    __syncthreads();
    for (int i = threadIdx.x; i < 1024; i += 256) {
        int h = i >> 5, w = i & 31;
        float a  = xs[(2 * h) * 65 + 2 * w],     bb = xs[(2 * h) * 65 + 2 * w + 1];
        float cc = xs[(2 * h + 1) * 65 + 2 * w], dd = xs[(2 * h + 1) * 65 + 2 * w + 1];
        wt[0][h * 33 + w] = 0.5f * (a + bb + cc + dd);
        wt[1][h * 33 + w] = 0.5f * (a + bb - cc - dd);
        wt[2][h * 33 + w] = 0.5f * (a - bb + cc - dd);
        wt[3][h * 33 + w] = 0.5f * (a - bb - cc + dd);
    }
    __syncthreads();
    float wk[4][9], tb[4];
#pragma unroll
    for (int k = 0; k < 4; ++k) {
        int ch = c * 4 + k;
        float sc = wav_scale[ch];
#pragma unroll
        for (int j = 0; j < 9; ++j) wk[k][j] = wav_w[ch * 9 + j] * sc;
        tb[k] = wav_b[ch] * sc;
    }
    float* upp = up + ((size_t)b * CG + c) * HW;
    for (int i = threadIdx.x; i < 1024; i += 256) {
        int h = i >> 5, w = i & 31;
        float tg[4];
#pragma unroll
    for (int k = 0; k < 4; ++k) {
            float s = tb[k];
#pragma unroll
            for (int dy = -1; dy <= 1; ++dy) {
                int hh = h + dy;
                if (hh < 0 || hh >= 32) continue;
#pragma unroll
                for (int dx = -1; dx <= 1; ++dx) {
                    int wx = w + dx;
                    if (wx < 0 || wx >= 32) continue;
                    s = fmaf(wt[k][hh * 33 + wx], wk[k][(dy + 1) * 3 + (dx + 1)], s);
                }
            }
            tg[k] = s;
        }
        float u00 = 0.5f * (tg[0] - tg[1] - tg[2] + tg[3]);
        float u01 = 0.5f * (tg[0] - tg[1] + tg[2] - tg[3]);
        float u10 = 0.5f * (tg[0] + tg[1] - tg[2] - tg[3]);
        float u11 = 0.5f * (tg[0] + tg[1] + tg[2] + tg[3]);
        upp[(2 * h) * 64 + 2 * w]         = u00;
        upp[(2 * h) * 64 + 2 * w + 1]     = u01;
        upp[(2 * h + 1) * 64 + 2 * w]     = u10;
        upp[(2 * h + 1) * 64 + 2 * w + 1] = u11;
    }
}

// ---------------------------------------------------------------------------
// SS2D input projection: xz = in_w(128x64) @ xg per pixel. Block per (b, h row).
// ---------------------------------------------------------------------------
__global__ __launch_bounds__(256) void k_inproj(const float* __restrict__ x,
                                                const float* __restrict__ in_w,
                                                float* __restrict__ xi,
                                                float* __restrict__ z) {
    int h = blockIdx.x, b = blockIdx.y;
    __shared__ float xs[64 * 65];        // [c][w]
    __shared__ float wl[128 * 64];
    for (int i = threadIdx.x; i < 64 * 64; i += 256) {
        int c = i >> 6, w = i & 63;
        xs[c * 65 + w] = x[((size_t)b * DIM + c) * HW + h * 64 + w];
    }
    for (int i = threadIdx.x; i < 128 * 64; i += 256) wl[i] = in_w[i];
    __syncthreads();
    int lane = threadIdx.x & 63;
    int wave = threadIdx.x >> 6;
    float acc[32];
#pragma unroll
    for (int oi = 0; oi < 32; ++oi) acc[oi] = 0.f;
    for (int c = 0; c < 64; ++c) {
        float xv = xs[c * 65 + lane];
#pragma unroll
        for (int oi = 0; oi < 32; ++oi)
            acc[oi] = fmaf(wl[(wave * 32 + oi) * 64 + c], xv, acc[oi]);
    }
#pragma unroll
    for (int oi = 0; oi < 32; ++oi) {
        int o = wave * 32 + oi;
        float* dst = (o < 64) ? (xi + ((size_t)b * 64 + o) * HW + h * 64)
                              : (z + ((size_t)b * 64 + (o - 64)) * HW + h * 64);
        dst[lane] = acc[oi];
    }
}

// ---------------------------------------------------------------------------
// xc = silu(depthwise3x3(xi) + cb). Block per (b, c) plane.
// ---------------------------------------------------------------------------
__global__ __launch_bounds__(256) void k_dwss(const float* __restrict__ xi,
                                              const float* __restrict__ cw,
                                              const float* __restrict__ cb,
                                              float* __restrict__ xc) {
    int c = blockIdx.x, b = blockIdx.y;
    __shared__ float t[66 * 66];
    const float* p = xi + ((size_t)b * 64 + c) * HW;
    for (int i = threadIdx.x; i < 66 * 66; i += 256) {
        int y = i / 66 - 1, xq = i % 66 - 1;
        t[i] = (y >= 0 && y < 64 && xq >= 0 && xq < 64) ? p[y * 64 + xq] : 0.f;
    }
    __syncthreads();
    float wk[9];
#pragma unroll
    for (int j = 0; j < 9; ++j) wk[j] = cw[c * 9 + j];
    float bias = cb[c];
    float* q = xc + ((size_t)b * 64 + c) * HW;
    for (int i = threadIdx.x; i < HW; i += 256) {
        int y = i >> 6, xq = i & 63;
        float s = bias;
#pragma unroll
        for (int dy = 0; dy < 3; ++dy)
#pragma unroll
            for (int dx = 0; dx < 3; ++dx)
                s = fmaf(t[(y + dy) * 66 + xq + dx], wk[dy * 3 + dx], s);
        q[i] = silu_f(s);
    }
}

// ---------------------------------------------------------------------------
// Per-pixel 6-way projections for both scan directions (dt[4], B, C).
// proj layout: [dir][b][l][8]
// ---------------------------------------------------------------------------
__global__ __launch_bounds__(256) void k_ssproj(const float* __restrict__ xc,
                                                const float* __restrict__ xpw,
                                                float* __restrict__ proj) {
    int h = blockIdx.x, b = blockIdx.y;
    __shared__ float xs[64 * 65];
    for (int i = threadIdx.x; i < 64 * 64; i += 256) {
        int c = i >> 6, w = i & 63;
        xs[c * 65 + w] = xc[((size_t)b * 64 + c) * HW + h * 64 + w];
    }
    __syncthreads();
    int w = threadIdx.x & 63;
    int j = threadIdx.x >> 6;
    for (int m = 0; m < 3; ++m) {
        int pidx = j * 3 + m;
        int dir = pidx / 6, e = pidx % 6;
        float s = 0.f;
        for (int c = 0; c < 64; ++c)
            s = fmaf(xs[c * 65 + w], xpw[(dir * 6 + e) * 64 + c], s);
        int l = (dir == 0) ? (h * 64 + w) : (w * 64 + h);
        proj[(((size_t)dir * NB + b) * HW + l) * 8 + e] = s;
    }
}

// ---------------------------------------------------------------------------
// Selective scan (N=1), segment-compose formulation.
// One wave per (b, dir, d) plane; lane owns 16 contiguous elems per 1024-chunk.
// Fast hw transcendentals (v_exp/v_log) in the delta/a computation.
// ---------------------------------------------------------------------------
__global__ __launch_bounds__(256) void k_scan(const float* __restrict__ xc,
                                              const float* __restrict__ proj,
                                              const float* __restrict__ dt_w,
                                              const float* __restrict__ dt_b,
                                              const float* __restrict__ A_log,
                                              const float* __restrict__ Dp,
                                              float* __restrict__ y0,
                                              float* __restrict__ y1) {
    int wave = threadIdx.x >> 6;
    int lane = threadIdx.x & 63;
    int wid = blockIdx.x * 4 + wave;
    int b = wid >> 7;
    int rem = wid & 127;
    int dir = rem >> 6;                  // uniform within a block (4 | 64)
    int d = rem & 63;
    int pd = dir * 64 + d;

    float4 wv = *(const float4*)(dt_w + pd * 4);
    float db = dt_b[pd];
    float A = -__expf(A_log[pd]);
    float Dv = Dp[pd];
    const float* pr = proj + ((size_t)dir * NB + b) * HW * 8;
    const float* uplane = xc + ((size_t)b * 64 + d) * HW;
    float* yp = ((dir == 0) ? y0 : y1) + ((size_t)b * 64 + d) * HW;

    __shared__ float lt[4][64 * 17];     // dir=1 transpose tile, padded
    float* myl = lt[wave];

    float carry = 0.f;
    for (int ch = 0; ch < 4; ++ch) {
        int e0 = ch * 1024 + lane * 16;  // first scan index of my segment
        float a[16], bv[16], cm[16], du[16];

        float uv[16];
        if (dir == 0) {
#pragma unroll
            for (int q = 0; q < 4; ++q) {
                float4 u4 = *(const float4*)(uplane + e0 + q * 4);
                uv[q * 4 + 0] = u4.x; uv[q * 4 + 1] = u4.y;
                uv[q * 4 + 2] = u4.z; uv[q * 4 + 3] = u4.w;
            }
        } else {
            int w_sp = e0 >> 6;          // fixed for all 16 elems of segment
            int h_sp0 = e0 & 63;
#pragma unroll
            for (int j = 0; j < 16; ++j) uv[j] = uplane[(h_sp0 + j) * 64 + w_sp];
        }

        float As = 1.f, Bs = 0.f;
#pragma unroll
        for (int j = 0; j < 16; ++j) {
            const float* pp = pr + (size_t)(e0 + j) * 8;
            float4 p4 = *(const float4*)pp;        // dt[0..3]
            float4 p5 = *(const float4*)(pp + 4);  // Bm, Cm, (pad)
            float pre = fmaf(p4.x, wv.x, fmaf(p4.y, wv.y,
                        fmaf(p4.z, wv.z, fmaf(p4.w, wv.w, db))));
            float delta = softplus_fast(pre);
            float aj = __expf(delta * A);
            float bj = delta * p5.x * uv[j];
            a[j] = aj; bv[j] = bj; cm[j] = p5.y; du[j] = Dv * uv[j];
            Bs = fmaf(aj, Bs, bj);       // compose segment map
            As *= aj;
        }

        // inclusive cross-lane scan of (As, Bs)
        float Ai = As, Bi = Bs;
#pragma unroll
        for (int off = 1; off < 64; off <<= 1) {
            float ap = __shfl_up(Ai, (unsigned)off, 64);
            float bp = __shfl_up(Bi, (unsigned)off, 64);
            if (lane >= off) { Bi = fmaf(Ai, bp, Bi); Ai *= ap; }
        }
        float ap1 = __shfl_up(Ai, 1, 64);
        float bp1 = __shfl_up(Bi, 1, 64);
        float h = (lane == 0) ? carry : fmaf(ap1, carry, bp1);
        float hend = fmaf(Ai, carry, Bi);
        carry = __shfl(hend, 63, 64);

        float y[16];
#pragma unroll
        for (int j = 0; j < 16; ++j) {
            h = fmaf(a[j], h, bv[j]);
            y[j] = fmaf(h, cm[j], du[j]);
        }

        if (dir == 0) {
            float4* dst = (float4*)(yp + e0);
#pragma unroll
            for (int q = 0; q < 4; ++q)
                dst[q] = make_float4(y[q * 4], y[q * 4 + 1], y[q * 4 + 2], y[q * 4 + 3]);
        } else {
            int wl = lane >> 2;
            int hs0 = (lane & 3) * 16;
#pragma unroll
            for (int j = 0; j < 16; ++j) myl[(hs0 + j) * 17 + wl] = y[j];
            __builtin_amdgcn_wave_barrier();
            int w0 = ch * 16;
            float4* dst = (float4*)(yp + lane * 64 + w0);
#pragma unroll
            for (int q = 0; q < 4; ++q)
                dst[q] = make_float4(myl[lane * 17 + q * 4 + 0],
                                     myl[lane * 17 + q * 4 + 1],
                                     myl[lane * 17 + q * 4 + 2],
                                     myl[lane * 17 + q * 4 + 3]);
            __builtin_amdgcn_wave_barrier();
        }
    }
}

// ---------------------------------------------------------------------------
// Final: y=(y0+y1)*silu(z); g = ow @ y (1x1 conv); out_g = base_scale*g + up
// ---------------------------------------------------------------------------
__global__ __launch_bounds__(256) void k_final(const float* __restrict__ y0,
                                               const float* __restrict__ y1,
                                               const float* __restrict__ z,
                                               const float* __restrict__ ow,
                                               const float* __restrict__ base_scale,
                                               const float* __restrict__ up,
                                               float* __restrict__ out) {
    int h = blockIdx.x, b = blockIdx.y;
    __shared__ float yv[64 * 65];
    __shared__ float wl[64 * 64];
    for (int i = threadIdx.x; i < 64 * 64; i += 256) {
        int c = i >> 6, w = i & 63;
        size_t idx = ((size_t)b * 64 + c) * HW + h * 64 + w;
        float zz = z[idx];
        yv[c * 65 + w] = (y0[idx] + y1[idx]) * silu_f(zz);
        wl[i] = ow[i];
    }
    __syncthreads();
    for (int i = threadIdx.x; i < 64 * 64; i += 256) {
        int o = i >> 6, w = i & 63;
        float s = 0.f;
        for (int c = 0; c < 64; ++c)
            s = fmaf(wl[o * 64 + c], yv[c * 65 + w], s);
        out[((size_t)b * DIM + o) * HW + h * 64 + w] =
            fmaf(base_scale[o], s, up[((size_t)b * CG + o) * HW + h * 64 + w]);
    }
}

// ---------------------------------------------------------------------------
extern "C" void kernel_launch(void* const* d_in, const int* in_sizes, int n_in,
                              void* d_out, int out_size, void* d_ws, size_t ws_size,
                              hipStream_t stream) {
    (void)in_sizes; (void)n_in; (void)out_size; (void)ws_size;
    const float* x = (const float*)d_in[0];
    float* out = (float*)d_out;
    float* ws = (float*)d_ws;

    const size_t IMG = (size_t)NB * 64 * HW;   // 4,194,304 floats
    float* buf_xi   = ws;                      // reused as y0 after consumption
    float* buf_z    = ws + IMG;
    float* buf_xc   = ws + 2 * IMG;
    float* buf_up   = ws + 3 * IMG;
    float* buf_y1   = ws + 4 * IMG;
    float* buf_proj = ws + 5 * IMG;            // 2*16*4096*8 = 1,048,576 floats
    float* buf_mean = buf_proj + (size_t)2 * NB * HW * 8;  // 1024
    float* buf_w3   = buf_mean + 1024;         // 16*64*9
    float* buf_w5   = buf_w3 + 16 * 64 * 9;    // 16*64*25
    float* buf_w7   = buf_w5 + 16 * 64 * 25;   // 16*64*49

    // ---- local branch ----
    k_mean<<<1024, 256, 0, stream>>>(x, buf_mean);
    k_weff<<<16, 64, 0, stream>>>(buf_mean, (const float*)d_in[1],
                                  (const float*)d_in[2], (const float*)d_in[3], buf_w3, 9);
    k_weff<<<16, 64, 0, stream>>>(buf_mean, (const float*)d_in[8],
                                  (const float*)d_in[9], (const float*)d_in[10], buf_w5, 25);
    k_weff<<<16, 64, 0, stream>>>(buf_mean, (const float*)d_in[15],
                                  (const float*)d_in[16], (const float*)d_in[17], buf_w7, 49);
    k_local<<<dim3(4, 64, 16), 256, 0, stream>>>(x, buf_w3, buf_w5, buf_w7,
        (const float*)d_in[4],  (const float*)d_in[5],  (const float*)d_in[6],  (const float*)d_in[7],
        (const float*)d_in[11], (const float*)d_in[12], (const float*)d_in[13], (const float*)d_in[14],
        (const float*)d_in[18], (const float*)d_in[19], (const float*)d_in[20], (const float*)d_in[21],
        out);

    // ---- wavelet branch (fused dec->conv->rec) ----
    k_up<<<dim3(64, 16), 256, 0, stream>>>(x, (const float*)d_in[22],
        (const float*)d_in[23], (const float*)d_in[24], buf_up);

    // ---- ss2d ----
    k_inproj<<<dim3(64, 16), 256, 0, stream>>>(x, (const float*)d_in[26], buf_xi, buf_z);
    k_dwss<<<dim3(64, 16), 256, 0, stream>>>(buf_xi, (const float*)d_in[27],
        (const float*)d_in[28], buf_xc);
    k_ssproj<<<dim3(64, 16), 256, 0, stream>>>(buf_xc, (const float*)d_in[29], buf_proj);
    k_scan<<<512, 256, 0, stream>>>(buf_xc, buf_proj,
        (const float*)d_in[30], (const float*)d_in[31],
        (const float*)d_in[32], (const float*)d_in[33],
        buf_xi /* y0 (xi is dead now) */, buf_y1);
    k_final<<<dim3(64, 16), 256, 0, stream>>>(buf_xi, buf_y1, buf_z,
        (const float*)d_in[34], (const float*)d_in[25], buf_up, out);

    // ---- passthrough ----
    k_copy_xi<<<(16 * 128 * HW / 4) / 256, 256, 0, stream>>>((const float4*)x, (float4*)out);
}